// Round 1
// baseline (449.020 us; speedup 1.0000x reference)
//
#include <hip/hip_runtime.h>
#include <hip/hip_bf16.h>
#include <math.h>

#define Bn   2
#define Nn   1024
#define DIMn 512
#define NHn  8
#define HDn  64
#define WINn 64
#define EPSF 1e-7f

// ---------------- wave helpers (wave64) ----------------
__device__ __forceinline__ float wsum(float v) {
#pragma unroll
  for (int m = 32; m >= 1; m >>= 1) v += __shfl_xor(v, m, 64);
  return v;
}
__device__ __forceinline__ float wmax(float v) {
#pragma unroll
  for (int m = 32; m >= 1; m >>= 1) v = fmaxf(v, __shfl_xor(v, m, 64));
  return v;
}

__device__ __forceinline__ float gelu_tanh(float x) {
  const float k0 = 0.7978845608028654f;  // sqrt(2/pi)
  float x3 = x * x * x;
  return 0.5f * x * (1.f + tanhf(k0 * (x + 0.044715f * x3)));
}

// ---------------- LayerNorm: one block (256 thr) per row of 512 ----------------
__global__ __launch_bounds__(256) void ln_kernel(const float* __restrict__ x,
                                                 const float* __restrict__ g,
                                                 const float* __restrict__ be,
                                                 float* __restrict__ y) {
  __shared__ float red[2][4];
  int row = blockIdx.x;
  int tid = threadIdx.x;
  const float* xr = x + (size_t)row * DIMn;
  float2 xv = *(const float2*)(xr + tid * 2);
  float s  = xv.x + xv.y;
  float s2 = xv.x * xv.x + xv.y * xv.y;
  s = wsum(s); s2 = wsum(s2);
  int wv = tid >> 6;
  if ((tid & 63) == 0) { red[0][wv] = s; red[1][wv] = s2; }
  __syncthreads();
  s  = red[0][0] + red[0][1] + red[0][2] + red[0][3];
  s2 = red[1][0] + red[1][1] + red[1][2] + red[1][3];
  float mean = s * (1.f / DIMn);
  float var  = s2 * (1.f / DIMn) - mean * mean;
  float rstd = rsqrtf(var + 1e-6f);
  int d = tid * 2;
  float2 gv = *(const float2*)(g + d);
  float2 bv = *(const float2*)(be + d);
  float2 o;
  o.x = (xv.x - mean) * rstd * gv.x + bv.x;
  o.y = (xv.y - mean) * rstd * gv.y + bv.y;
  *(float2*)(y + (size_t)row * DIMn + d) = o;
}

// ---------------- tiled fp32 GEMM, C = A(MxK) @ W(KxN) + bias [EPI: 0=bias,1=+res,2=gelu] ----------------
template <int EPI>
__global__ __launch_bounds__(256) void gemm_ep(const float* __restrict__ A,
                                               const float* __restrict__ W,
                                               const float* __restrict__ bias,
                                               const float* __restrict__ res,
                                               float* __restrict__ C,
                                               int M, int N, int K) {
  __shared__ __align__(16) float As[16][68];  // [k][m], stride 68 breaks conflicts, keeps 16B align
  __shared__ __align__(16) float Bs[16][64];  // [k][n]
  int tid = threadIdx.x;
  int tx = tid & 15, ty = tid >> 4;
  int bn = blockIdx.x * 64, bm = blockIdx.y * 64;
  float acc[4][4] = {{0.f}};

  int i4 = tid * 4;
  int am = i4 >> 4, ak = i4 & 15;   // A tile: 64 rows x 16 k
  int bk = i4 >> 6, bn2 = i4 & 63;  // B tile: 16 k x 64 n
  const float* Ap = A + (size_t)(bm + am) * K + ak;
  const float* Wp = W + (size_t)bk * N + bn + bn2;

  for (int k0 = 0; k0 < K; k0 += 16) {
    float4 a4 = *(const float4*)(Ap + k0);
    float4 b4 = *(const float4*)(Wp + (size_t)k0 * N);
    As[ak + 0][am] = a4.x; As[ak + 1][am] = a4.y;
    As[ak + 2][am] = a4.z; As[ak + 3][am] = a4.w;
    *(float4*)&Bs[bk][bn2] = b4;
    __syncthreads();
#pragma unroll
    for (int kk = 0; kk < 16; ++kk) {
      float4 av = *(const float4*)&As[kk][ty * 4];
      float4 bv = *(const float4*)&Bs[kk][tx * 4];
      float a[4] = {av.x, av.y, av.z, av.w};
      float b[4] = {bv.x, bv.y, bv.z, bv.w};
#pragma unroll
      for (int i = 0; i < 4; ++i)
#pragma unroll
        for (int j = 0; j < 4; ++j) acc[i][j] = fmaf(a[i], b[j], acc[i][j]);
    }
    __syncthreads();
  }

  int m0 = bm + ty * 4, n0 = bn + tx * 4;
#pragma unroll
  for (int i = 0; i < 4; ++i) {
    size_t rowoff = (size_t)(m0 + i) * N + n0;
    float4 cv;
    float* cp = &cv.x;
#pragma unroll
    for (int j = 0; j < 4; ++j) {
      float val = acc[i][j] + bias[n0 + j];
      if (EPI == 1) val += res[rowoff + j];
      if (EPI == 2) val = gelu_tanh(val);
      cp[j] = val;
    }
    *(float4*)(C + rowoff) = cv;
  }
}

// ---------------- hash-offset + RoPE + expmap0 for q and k; one wave per (b,n,h) ----------------
__global__ __launch_bounds__(64) void rope_exp_kernel(float* __restrict__ q,
                                                      float* __restrict__ k,
                                                      const float* __restrict__ fcos,
                                                      const float* __restrict__ fsin,
                                                      const float* __restrict__ cvec,
                                                      const float* __restrict__ hash) {
  int lane = threadIdx.x;         // d in [0,64)
  int bid = blockIdx.x;           // ((b*N + n)*NH + h)
  int h = bid & 7;
  int n = (bid >> 3) & (Nn - 1);
  int b = bid >> 13;
  size_t base = (size_t)bid * HDn;
  int dr = lane & 31;
  float cs = fcos[n * 32 + dr], sn = fsin[n * 32 + dr];
  const float LOG9 = 2.1972245773362196f;  // log(1+HASH_WIN)

  float qr = q[base + dr]      + hash[h * HDn + dr] * LOG9;
  float qi = q[base + dr + 32] + hash[h * HDn + dr + 32] * LOG9;
  float qv = (lane < 32) ? (qr * cs - qi * sn) : (qr * sn + qi * cs);
  float kr = k[base + dr];
  float ki = k[base + dr + 32];
  float kv = (lane < 32) ? (kr * cs - ki * sn) : (kr * sn + ki * cs);

  float c = cvec[b];
  float sqc = sqrtf(c);  // c in [0.1,1] -> no clip needed

  float nq = sqrtf(wsum(qv * qv));
  float nk = sqrtf(wsum(kv * kv));
  float sq = fmaxf(nq, EPSF);
  float sk = fmaxf(nk, EPSF);
  float oq = (nq < EPSF) ? 0.f : (tanhf(sqc * sq) / sqc) * (qv / sq);
  float ok = (nk < EPSF) ? 0.f : (tanhf(sqc * sk) / sqc) * (kv / sk);
  q[base + lane] = oq;
  k[base + lane] = ok;
}

// ---------------- windowed Poincare attention; block = (b,h, 32 queries) ----------------
__global__ __launch_bounds__(256) void attn_kernel(const float* __restrict__ qh,
                                                   const float* __restrict__ kh,
                                                   const float* __restrict__ v,
                                                   const float* __restrict__ cvec,
                                                   const float* __restrict__ geo,
                                                   float* __restrict__ attn_out) {
  __shared__ float Ks[95][65];
  __shared__ float Vs[95][65];
  __shared__ float Qs[32][65];
  int tid = threadIdx.x;
  int bid = blockIdx.x;  // B*NH*(N/32) = 512
  int nt = bid & 31;
  int h = (bid >> 5) & 7;
  int b = bid >> 8;
  int n0 = nt * 32;

  // stage K/V rows [n0-63, n0+31] (zero-pad left) and Q rows [n0, n0+31]
  for (int i = tid; i < 95 * 64; i += 256) {
    int r = i >> 6, d = i & 63;
    int gi = n0 - 63 + r;
    float kk = 0.f, vv = 0.f;
    if (gi >= 0) {
      size_t addr = ((size_t)((b * Nn + gi) * NHn + h)) * HDn + d;
      kk = kh[addr]; vv = v[addr];
    }
    Ks[r][d] = kk; Vs[r][d] = vv;
  }
  for (int i = tid; i < 32 * 64; i += 256) {
    int r = i >> 6, d = i & 63;
    Qs[r][d] = qh[((size_t)((b * Nn + n0 + r) * NHn + h)) * HDn + d];
  }
  __syncthreads();

  float c = cvec[b];
  float sqc = sqrtf(c);
  float gs = geo[h];
  int wv = tid >> 6, lane = tid & 63;

  for (int nl = wv; nl < 32; nl += 4) {
    float qd = Qs[nl][lane];
    float x2 = wsum(qd * qd);
    // lane = window position j; key row = nl + j
    float xy = 0.f, y2 = 0.f;
    int row = nl + lane;
#pragma unroll 16
    for (int d = 0; d < 64; ++d) {
      float qb = Qs[nl][d];
      float kk = Ks[row][d];
      xy = fmaf(qb, kk, xy);
      y2 = fmaf(kk, kk, y2);
    }
    // Poincare distance from scalars (fp64 chain: atanh arg can be ~1-5e-6)
    double cd = c, xyd = xy, y2d = y2, x2d = x2;
    double alpha = 1.0 - 2.0 * cd * xyd + cd * y2d;
    double beta  = 1.0 - cd * x2d;
    double den = 1.0 - 2.0 * cd * xyd + cd * cd * x2d * y2d;
    den = den > 1e-7 ? den : 1e-7;
    double dn2 = alpha * alpha * x2d - 2.0 * alpha * beta * xyd + beta * beta * y2d;
    dn2 = dn2 > 0.0 ? dn2 : 0.0;
    double dn = sqrt(dn2) / den;
    dn = dn > 1e-7 ? dn : 1e-7;
    double arg = (double)sqc * dn;
    if (arg > 0.9999999) arg = 0.9999999;
    double dist = log((1.0 + arg) / (1.0 - arg)) / (double)sqc;  // 2*atanh(arg)/sqc
    float sc = (float)(-(double)gs * dist);

    // softmax over 64 window positions
    float mx = wmax(sc);
    float e = expf(sc - mx);
    float se = wsum(e);
    float w = e / se;

    // attn_d = sum_j w_j * V[nl+j][d]; lane = d, broadcast w_j via shuffle
    float acc = 0.f;
#pragma unroll 16
    for (int j = 0; j < 64; ++j) {
      float wj = __shfl(w, j, 64);
      acc = fmaf(wj, Vs[nl + j][lane], acc);
    }
    attn_out[((size_t)((b * Nn + n0 + nl) * NHn + h)) * HDn + lane] = acc;
  }
}

// ---------------- launcher ----------------
extern "C" void kernel_launch(void* const* d_in, const int* in_sizes, int n_in,
                              void* d_out, int out_size, void* d_ws, size_t ws_size,
                              hipStream_t stream) {
  const float* x    = (const float*)d_in[0];
  const float* fcos = (const float*)d_in[1];
  const float* fsin = (const float*)d_in[2];
  const float* cvec = (const float*)d_in[3];
  const float* Wq = (const float*)d_in[4];  const float* bq = (const float*)d_in[5];
  const float* Wk = (const float*)d_in[6];  const float* bk = (const float*)d_in[7];
  const float* Wv = (const float*)d_in[8];  const float* bv = (const float*)d_in[9];
  const float* Wo = (const float*)d_in[10]; const float* bo = (const float*)d_in[11];
  const float* W1 = (const float*)d_in[12]; const float* b1 = (const float*)d_in[13];
  const float* W2 = (const float*)d_in[14]; const float* b2 = (const float*)d_in[15];
  const float* ln1s = (const float*)d_in[16]; const float* ln1b = (const float*)d_in[17];
  const float* ln2s = (const float*)d_in[18]; const float* ln2b = (const float*)d_in[19];
  const float* geo  = (const float*)d_in[20]; const float* hash = (const float*)d_in[21];
  float* out = (float*)d_out;
  float* ws = (float*)d_ws;

  const size_t TOK = (size_t)Bn * Nn * DIMn;  // 1,048,576
  float* bufA = ws;            // xn, later attn
  float* bufB = ws + TOK;      // q_h, later LN2 out
  float* bufC = ws + 2 * TOK;  // k_h, later mid (spans C+D+...)
  float* bufD = ws + 3 * TOK;  // v
  float* mid  = ws + 2 * TOK;  // 4*TOK floats (reuses k,v) -> [2T, 6T)
  float* xout = ws + 6 * TOK;  // [6T, 7T)

  const int M = Bn * Nn;  // 2048

  // 1) LN1
  ln_kernel<<<M, 256, 0, stream>>>(x, ln1s, ln1b, bufA);
  // 2) QKV
  gemm_ep<0><<<dim3(DIMn / 64, M / 64), 256, 0, stream>>>(bufA, Wq, bq, nullptr, bufB, M, DIMn, DIMn);
  gemm_ep<0><<<dim3(DIMn / 64, M / 64), 256, 0, stream>>>(bufA, Wk, bk, nullptr, bufC, M, DIMn, DIMn);
  gemm_ep<0><<<dim3(DIMn / 64, M / 64), 256, 0, stream>>>(bufA, Wv, bv, nullptr, bufD, M, DIMn, DIMn);
  // 3) hash + RoPE + expmap0 (in place on q,k)
  rope_exp_kernel<<<Bn * Nn * NHn, 64, 0, stream>>>(bufB, bufC, fcos, fsin, cvec, hash);
  // 4) windowed Poincare attention -> bufA (B,N,NH,HD) == (B,N,DIM)
  attn_kernel<<<Bn * NHn * (Nn / 32), 256, 0, stream>>>(bufB, bufC, bufD, cvec, geo, bufA);
  // 5) out proj + residual(x)
  gemm_ep<1><<<dim3(DIMn / 64, M / 64), 256, 0, stream>>>(bufA, Wo, bo, x, xout, M, DIMn, DIMn);
  // 6) LN2
  ln_kernel<<<M, 256, 0, stream>>>(xout, ln2s, ln2b, bufB);
  // 7) FFN1 + gelu
  gemm_ep<2><<<dim3(4 * DIMn / 64, M / 64), 256, 0, stream>>>(bufB, W1, b1, nullptr, mid, M, 4 * DIMn, DIMn);
  // 8) FFN2 + residual(xout) -> out
  gemm_ep<1><<<dim3(DIMn / 64, M / 64), 256, 0, stream>>>(mid, W2, b2, xout, out, M, DIMn, 4 * DIMn);
}

// Round 2
// 237.517 us; speedup vs baseline: 1.8905x; 1.8905x over previous
//
#include <hip/hip_runtime.h>
#include <math.h>
#include <stdint.h>

#define Bn   2
#define Nn   1024
#define DIMn 512
#define NHn  8
#define HDn  64
#define QKVS 1536
#define EPSF 1e-7f

typedef __attribute__((ext_vector_type(8))) short short8;
typedef __attribute__((ext_vector_type(4))) float floatx4;

// ---------------- bf16 helpers (RNE) ----------------
__device__ __forceinline__ unsigned short f2bf(float f) {
  union { float f; uint32_t u; } v; v.f = f;
  uint32_t u = v.u;
  return (unsigned short)((u + 0x7FFFu + ((u >> 16) & 1u)) >> 16);
}
__device__ __forceinline__ float bf2f(unsigned short h) {
  union { uint32_t u; float f; } v; v.u = ((uint32_t)h) << 16;
  return v.f;
}

// ---------------- wave helpers (wave64) ----------------
__device__ __forceinline__ float wsum(float v) {
#pragma unroll
  for (int m = 32; m >= 1; m >>= 1) v += __shfl_xor(v, m, 64);
  return v;
}
__device__ __forceinline__ float wmax(float v) {
#pragma unroll
  for (int m = 32; m >= 1; m >>= 1) v = fmaxf(v, __shfl_xor(v, m, 64));
  return v;
}

__device__ __forceinline__ float gelu_tanh(float x) {
  const float k0 = 0.7978845608028654f;  // sqrt(2/pi)
  float x3 = x * x * x;
  return 0.5f * x * (1.f + tanhf(k0 * (x + 0.044715f * x3)));
}

// ---------------- async global->LDS 16B ----------------
__device__ __forceinline__ void glds16(const unsigned short* g, unsigned short* l) {
  __builtin_amdgcn_global_load_lds((const __attribute__((address_space(1))) void*)g,
                                   (__attribute__((address_space(3))) void*)l, 16, 0, 0);
}

// ---------------- weight transpose + bf16 convert (+ bias concat) ----------------
// ranges: [0,256) Wq, [256,512) Wk, [512,768) Wv, [768,1024) Wo, [1024,2048) W1,
//         [2048,3072) W2, 3072 = bias concat
__global__ __launch_bounds__(256) void convT_all(
    const float* __restrict__ Wq, const float* __restrict__ Wk,
    const float* __restrict__ Wv, const float* __restrict__ Wo,
    const float* __restrict__ W1, const float* __restrict__ W2,
    unsigned short* __restrict__ Wcat_hi, unsigned short* __restrict__ Wcat_lo,
    unsigned short* __restrict__ Wo_t, unsigned short* __restrict__ W1_t,
    unsigned short* __restrict__ W2_t,
    const float* __restrict__ bq, const float* __restrict__ bk,
    const float* __restrict__ bv, float* __restrict__ bias_cat) {
  __shared__ float t[32][33];
  int bid = blockIdx.x;
  int tid = threadIdx.x;
  if (bid >= 3072) {  // bias concat
    for (int i = tid; i < 512; i += 256) {
      bias_cat[i] = bq[i];
      bias_cat[512 + i] = bk[i];
      bias_cat[1024 + i] = bv[i];
    }
    return;
  }
  const float* W;
  unsigned short* hi;
  unsigned short* lo = nullptr;
  int K, N, tix;
  if (bid < 256)       { W = Wq; hi = Wcat_hi;               lo = Wcat_lo;               K = 512;  N = 512;  tix = bid; }
  else if (bid < 512)  { W = Wk; hi = Wcat_hi + 512 * 512;   lo = Wcat_lo + 512 * 512;   K = 512;  N = 512;  tix = bid - 256; }
  else if (bid < 768)  { W = Wv; hi = Wcat_hi + 1024 * 512;  lo = Wcat_lo + 1024 * 512;  K = 512;  N = 512;  tix = bid - 512; }
  else if (bid < 1024) { W = Wo; hi = Wo_t;                  K = 512;  N = 512;  tix = bid - 768; }
  else if (bid < 2048) { W = W1; hi = W1_t;                  K = 512;  N = 2048; tix = bid - 1024; }
  else                 { W = W2; hi = W2_t;                  K = 2048; N = 512;  tix = bid - 2048; }
  int ntn = N >> 5;
  int kt = tix / ntn, nt = tix - kt * ntn;
  int k0 = kt * 32, n0 = nt * 32;
  for (int i = tid; i < 1024; i += 256) {
    int r = i >> 5, c = i & 31;
    t[r][c] = W[(size_t)(k0 + r) * N + n0 + c];
  }
  __syncthreads();
  for (int i = tid; i < 1024; i += 256) {
    int r = i >> 5, c = i & 31;  // r = local n, c = local k
    float v = t[c][r];
    unsigned short h = f2bf(v);
    size_t oi = (size_t)(n0 + r) * K + k0 + c;
    hi[oi] = h;
    if (lo) lo[oi] = f2bf(v - bf2f(h));
  }
}

// ---------------- LayerNorm -> bf16 (optionally hi+lo split) ----------------
template <int SPLIT>
__global__ __launch_bounds__(256) void ln_kernel(const float* __restrict__ x,
                                                 const float* __restrict__ g,
                                                 const float* __restrict__ be,
                                                 unsigned short* __restrict__ yhi,
                                                 unsigned short* __restrict__ ylo) {
  __shared__ float red[2][4];
  int row = blockIdx.x;
  int tid = threadIdx.x;
  const float* xr = x + (size_t)row * DIMn;
  float2 xv = *(const float2*)(xr + tid * 2);
  float s  = xv.x + xv.y;
  float s2 = xv.x * xv.x + xv.y * xv.y;
  s = wsum(s); s2 = wsum(s2);
  int wv = tid >> 6;
  if ((tid & 63) == 0) { red[0][wv] = s; red[1][wv] = s2; }
  __syncthreads();
  s  = red[0][0] + red[0][1] + red[0][2] + red[0][3];
  s2 = red[1][0] + red[1][1] + red[1][2] + red[1][3];
  float mean = s * (1.f / DIMn);
  float var  = s2 * (1.f / DIMn) - mean * mean;
  float rstd = rsqrtf(var + 1e-6f);
  int d = tid * 2;
  float2 gv = *(const float2*)(g + d);
  float2 bv = *(const float2*)(be + d);
  float o0 = (xv.x - mean) * rstd * gv.x + bv.x;
  float o1 = (xv.y - mean) * rstd * gv.y + bv.y;
  size_t idx = (size_t)row * DIMn + d;
  unsigned short h0 = f2bf(o0), h1 = f2bf(o1);
  ushort2 hv; hv.x = h0; hv.y = h1;
  *(ushort2*)(yhi + idx) = hv;
  if (SPLIT) {
    ushort2 lv; lv.x = f2bf(o0 - bf2f(h0)); lv.y = f2bf(o1 - bf2f(h1));
    *(ushort2*)(ylo + idx) = lv;
  }
}

// ---------------- bf16 MFMA GEMM: C = A @ Bt^T (+bias, EPI, optional split-bf16) ----
// A [M][K] bf16 (hi/lo), Bt [N][K] bf16 (hi/lo). EPI: 0=bias, 1=bias+res, 2=bias+gelu.
template <int BM, int BN, int SPLIT, int EPI, int OUTBF16>
__global__ __launch_bounds__(256) void gemm_mfma(
    const unsigned short* __restrict__ Ahi, const unsigned short* __restrict__ Alo,
    const unsigned short* __restrict__ Bhi, const unsigned short* __restrict__ Blo,
    const float* __restrict__ bias, const float* __restrict__ res,
    void* __restrict__ outp, int M, int N, int K) {
  constexpr int BK = 32;
  constexpr int FI = BM / 32, FJ = BN / 32;
  constexpr int AE = BM * BK, BE = BN * BK;
  __shared__ unsigned short smem[(SPLIT + 1) * (AE + BE)];
  unsigned short* AsHi = smem;
  unsigned short* AsLo = smem + (SPLIT ? AE : 0);
  unsigned short* BsHi = smem + (SPLIT + 1) * AE;
  unsigned short* BsLo = BsHi + (SPLIT ? BE : 0);

  int tid = threadIdx.x;
  int lane = tid & 63;
  int wid = tid >> 6;
  int wm = (wid >> 1) * (BM / 2), wn = (wid & 1) * (BN / 2);
  int bm = blockIdx.y * BM, bn = blockIdx.x * BN;
  int m16 = lane & 15, kg = lane >> 4;

  floatx4 acc[FI][FJ];
#pragma unroll
  for (int i = 0; i < FI; ++i)
#pragma unroll
    for (int j = 0; j < FJ; ++j) { floatx4 z = {0.f, 0.f, 0.f, 0.f}; acc[i][j] = z; }

  const unsigned short* aph = Ahi + (size_t)bm * K;
  const unsigned short* bph = Bhi + (size_t)bn * K;
  const unsigned short* apl = SPLIT ? (Alo + (size_t)bm * K) : nullptr;
  const unsigned short* bpl = SPLIT ? (Blo + (size_t)bn * K) : nullptr;

  for (int k0 = 0; k0 < K; k0 += BK) {
#pragma unroll
    for (int c = tid; c < BM * 4; c += 256) {
      int row = c >> 2, kk = (c & 3) * 8;
      glds16(aph + (size_t)row * K + k0 + kk, AsHi + c * 8);
      if constexpr (SPLIT) glds16(apl + (size_t)row * K + k0 + kk, AsLo + c * 8);
    }
#pragma unroll
    for (int c = tid; c < BN * 4; c += 256) {
      int row = c >> 2, kk = (c & 3) * 8;
      glds16(bph + (size_t)row * K + k0 + kk, BsHi + c * 8);
      if constexpr (SPLIT) glds16(bpl + (size_t)row * K + k0 + kk, BsLo + c * 8);
    }
    __syncthreads();

    short8 ah[FI], bh[FJ];
    short8 al[SPLIT ? FI : 1], bl[SPLIT ? FJ : 1];
#pragma unroll
    for (int i = 0; i < FI; ++i) {
      int r = wm + i * 16 + m16;
      ah[i] = *(const short8*)&AsHi[r * BK + kg * 8];
      if constexpr (SPLIT) al[i] = *(const short8*)&AsLo[r * BK + kg * 8];
    }
#pragma unroll
    for (int j = 0; j < FJ; ++j) {
      int r = wn + j * 16 + m16;
      bh[j] = *(const short8*)&BsHi[r * BK + kg * 8];
      if constexpr (SPLIT) bl[j] = *(const short8*)&BsLo[r * BK + kg * 8];
    }
#pragma unroll
    for (int i = 0; i < FI; ++i)
#pragma unroll
      for (int j = 0; j < FJ; ++j) {
        acc[i][j] = __builtin_amdgcn_mfma_f32_16x16x32_bf16(ah[i], bh[j], acc[i][j], 0, 0, 0);
        if constexpr (SPLIT) {
          acc[i][j] = __builtin_amdgcn_mfma_f32_16x16x32_bf16(al[i], bh[j], acc[i][j], 0, 0, 0);
          acc[i][j] = __builtin_amdgcn_mfma_f32_16x16x32_bf16(ah[i], bl[j], acc[i][j], 0, 0, 0);
        }
      }
    __syncthreads();
  }

  // epilogue: C/D map col=lane&15, row=(lane>>4)*4+reg  [m89/m91-verified]
#pragma unroll
  for (int i = 0; i < FI; ++i) {
    int gr0 = bm + wm + i * 16 + kg * 4;
#pragma unroll
    for (int j = 0; j < FJ; ++j) {
      int gc = bn + wn + j * 16 + m16;
      float bsv = bias[gc];
#pragma unroll
      for (int r = 0; r < 4; ++r) {
        size_t idx = (size_t)(gr0 + r) * N + gc;
        float v = acc[i][j][r] + bsv;
        if constexpr (EPI == 1) v += res[idx];
        if constexpr (EPI == 2) v = gelu_tanh(v);
        if constexpr (OUTBF16) ((unsigned short*)outp)[idx] = f2bf(v);
        else ((float*)outp)[idx] = v;
      }
    }
  }
}

// ---------------- hash-offset + RoPE + expmap0 (in place in qkv, fp32) -------------
__global__ __launch_bounds__(64) void rope_exp_kernel(float* __restrict__ qkv,
                                                      const float* __restrict__ fcos,
                                                      const float* __restrict__ fsin,
                                                      const float* __restrict__ cvec,
                                                      const float* __restrict__ hash) {
  int lane = threadIdx.x;
  int bid = blockIdx.x;  // ((b*N + n)*NH + h)
  int h = bid & 7;
  int n = (bid >> 3) & (Nn - 1);
  int b = bid >> 13;
  size_t baseq = (size_t)(b * Nn + n) * QKVS + h * HDn;
  size_t basek = baseq + 512;
  int dr = lane & 31;
  float cs = fcos[n * 32 + dr], sn = fsin[n * 32 + dr];
  const float LOG9 = 2.1972245773362196f;

  float qr = qkv[baseq + dr]      + hash[h * HDn + dr] * LOG9;
  float qi = qkv[baseq + dr + 32] + hash[h * HDn + dr + 32] * LOG9;
  float qv = (lane < 32) ? (qr * cs - qi * sn) : (qr * sn + qi * cs);
  float kr = qkv[basek + dr];
  float ki = qkv[basek + dr + 32];
  float kv = (lane < 32) ? (kr * cs - ki * sn) : (kr * sn + ki * cs);

  float c = cvec[b];
  float sqc = sqrtf(c);

  float nq = sqrtf(wsum(qv * qv));
  float nk = sqrtf(wsum(kv * kv));
  float sq = fmaxf(nq, EPSF);
  float sk = fmaxf(nk, EPSF);
  float oq = (nq < EPSF) ? 0.f : (tanhf(sqc * sq) / sqc) * (qv / sq);
  float ok = (nk < EPSF) ? 0.f : (tanhf(sqc * sk) / sqc) * (kv / sk);
  qkv[baseq + lane] = oq;
  qkv[basek + lane] = ok;
}

// ---------------- windowed Poincare attention (fp32 math, bf16 out) ----------------
__global__ __launch_bounds__(256) void attn_kernel(const float* __restrict__ qkv,
                                                   const float* __restrict__ cvec,
                                                   const float* __restrict__ geo,
                                                   unsigned short* __restrict__ attn_out) {
  __shared__ float Ks[95][65];
  __shared__ float Vs[95][65];
  __shared__ float Qs[32][65];
  int tid = threadIdx.x;
  int bid = blockIdx.x;  // B*NH*(N/32) = 512
  int nt = bid & 31;
  int h = (bid >> 5) & 7;
  int b = bid >> 8;
  int n0 = nt * 32;

  for (int i = tid; i < 95 * 64; i += 256) {
    int r = i >> 6, d = i & 63;
    int gi = n0 - 63 + r;
    float kk = 0.f, vv = 0.f;
    if (gi >= 0) {
      size_t addr = (size_t)(b * Nn + gi) * QKVS + h * HDn + d;
      kk = qkv[addr + 512]; vv = qkv[addr + 1024];
    }
    Ks[r][d] = kk; Vs[r][d] = vv;
  }
  for (int i = tid; i < 32 * 64; i += 256) {
    int r = i >> 6, d = i & 63;
    Qs[r][d] = qkv[(size_t)(b * Nn + n0 + r) * QKVS + h * HDn + d];
  }
  __syncthreads();

  float c = cvec[b];
  float sqc = sqrtf(c);
  float gs = geo[h];
  int wv = tid >> 6, lane = tid & 63;

  for (int nl = wv; nl < 32; nl += 4) {
    float qd = Qs[nl][lane];
    float x2 = wsum(qd * qd);
    float xy = 0.f, y2 = 0.f;
    int row = nl + lane;
#pragma unroll 16
    for (int d = 0; d < 64; ++d) {
      float qb = Qs[nl][d];
      float kk = Ks[row][d];
      xy = fmaf(qb, kk, xy);
      y2 = fmaf(kk, kk, y2);
    }
    double cd = c, xyd = xy, y2d = y2, x2d = x2;
    double alpha = 1.0 - 2.0 * cd * xyd + cd * y2d;
    double beta  = 1.0 - cd * x2d;
    double den = 1.0 - 2.0 * cd * xyd + cd * cd * x2d * y2d;
    den = den > 1e-7 ? den : 1e-7;
    double dn2 = alpha * alpha * x2d - 2.0 * alpha * beta * xyd + beta * beta * y2d;
    dn2 = dn2 > 0.0 ? dn2 : 0.0;
    double dn = sqrt(dn2) / den;
    dn = dn > 1e-7 ? dn : 1e-7;
    double arg = (double)sqc * dn;
    if (arg > 0.9999999) arg = 0.9999999;
    double dist = log((1.0 + arg) / (1.0 - arg)) / (double)sqc;
    float sc = (float)(-(double)gs * dist);

    float mx = wmax(sc);
    float e = expf(sc - mx);
    float se = wsum(e);
    float w = e / se;

    float acc = 0.f;
#pragma unroll 16
    for (int j = 0; j < 64; ++j) {
      float wj = __shfl(w, j, 64);
      acc = fmaf(wj, Vs[nl + j][lane], acc);
    }
    attn_out[(size_t)(b * Nn + n0 + nl) * DIMn + h * HDn + lane] = f2bf(acc);
  }
}

// ---------------- launcher ----------------
extern "C" void kernel_launch(void* const* d_in, const int* in_sizes, int n_in,
                              void* d_out, int out_size, void* d_ws, size_t ws_size,
                              hipStream_t stream) {
  const float* x    = (const float*)d_in[0];
  const float* fcos = (const float*)d_in[1];
  const float* fsin = (const float*)d_in[2];
  const float* cvec = (const float*)d_in[3];
  const float* Wq = (const float*)d_in[4];  const float* bq = (const float*)d_in[5];
  const float* Wk = (const float*)d_in[6];  const float* bk = (const float*)d_in[7];
  const float* Wv = (const float*)d_in[8];  const float* bv = (const float*)d_in[9];
  const float* Wo = (const float*)d_in[10]; const float* bo = (const float*)d_in[11];
  const float* W1 = (const float*)d_in[12]; const float* b1 = (const float*)d_in[13];
  const float* W2 = (const float*)d_in[14]; const float* b2 = (const float*)d_in[15];
  const float* ln1s = (const float*)d_in[16]; const float* ln1b = (const float*)d_in[17];
  const float* ln2s = (const float*)d_in[18]; const float* ln2b = (const float*)d_in[19];
  const float* geo  = (const float*)d_in[20]; const float* hash = (const float*)d_in[21];
  float* out = (float*)d_out;
  char* base = (char*)d_ws;

  // workspace layout (bytes)
  unsigned short* Wcat_hi = (unsigned short*)(base + 0);         // 1536x512 bf16
  unsigned short* Wcat_lo = (unsigned short*)(base + 1572864);
  unsigned short* Wo_t    = (unsigned short*)(base + 3145728);   // 512x512
  unsigned short* W1_t    = (unsigned short*)(base + 3670016);   // 2048x512
  unsigned short* W2_t    = (unsigned short*)(base + 5767168);   // 512x2048
  unsigned short* xn_hi   = (unsigned short*)(base + 7864320);   // 2048x512
  unsigned short* xn_lo   = (unsigned short*)(base + 9961472);
  float*          qkv     = (float*)(base + 12058624);           // 2048x1536 f32
  unsigned short* attnb   = (unsigned short*)(base + 7864320);   // reuse xn_hi
  float*          xout    = (float*)(base + 9961472);            // 2048x512 f32 (reuse)
  unsigned short* hbuf    = (unsigned short*)(base + 14155776);  // 2048x512
  unsigned short* mid     = (unsigned short*)(base + 16252928);  // 2048x2048
  float*          bias_cat= (float*)(base + 24641536);           // 1536 f32

  const int M = Bn * Nn;  // 2048

  // 1) weight transpose/convert + bias concat
  convT_all<<<3073, 256, 0, stream>>>(Wq, Wk, Wv, Wo, W1, W2, Wcat_hi, Wcat_lo,
                                      Wo_t, W1_t, W2_t, bq, bk, bv, bias_cat);
  // 2) LN1 -> split bf16
  ln_kernel<1><<<M, 256, 0, stream>>>(x, ln1s, ln1b, xn_hi, xn_lo);
  // 3) fused QKV GEMM (split-bf16 x2 precision) -> qkv f32 [M][1536]
  gemm_mfma<64, 64, 1, 0, 0><<<dim3(QKVS / 64, M / 64), 256, 0, stream>>>(
      xn_hi, xn_lo, Wcat_hi, Wcat_lo, bias_cat, nullptr, qkv, M, QKVS, 512);
  // 4) hash + RoPE + expmap0 in place
  rope_exp_kernel<<<Bn * Nn * NHn, 64, 0, stream>>>(qkv, fcos, fsin, cvec, hash);
  // 5) windowed Poincare attention -> attnb bf16 [M][512]
  attn_kernel<<<Bn * NHn * (Nn / 32), 256, 0, stream>>>(qkv, cvec, geo, attnb);
  // 6) Wo + residual(x) -> xout f32
  gemm_mfma<64, 64, 0, 1, 0><<<dim3(DIMn / 64, M / 64), 256, 0, stream>>>(
      attnb, nullptr, Wo_t, nullptr, bo, x, xout, M, DIMn, 512);
  // 7) LN2 -> hbuf bf16
  ln_kernel<0><<<M, 256, 0, stream>>>(xout, ln2s, ln2b, hbuf, nullptr);
  // 8) FFN1 + gelu -> mid bf16
  gemm_mfma<128, 128, 0, 2, 1><<<dim3(2048 / 128, M / 128), 256, 0, stream>>>(
      hbuf, nullptr, W1_t, nullptr, b1, nullptr, mid, M, 2048, 512);
  // 9) FFN2 + residual(xout) -> out f32
  gemm_mfma<64, 64, 0, 1, 0><<<dim3(DIMn / 64, M / 64), 256, 0, stream>>>(
      mid, nullptr, W2_t, nullptr, b2, xout, out, M, DIMn, 2048);
}

// Round 3
// 227.639 us; speedup vs baseline: 1.9725x; 1.0434x over previous
//
#include <hip/hip_runtime.h>
#include <math.h>
#include <stdint.h>

#define Bn   2
#define Nn   1024
#define DIMn 512
#define NHn  8
#define HDn  64
#define QKVS 1536
#define EPSF 1e-7f

typedef __attribute__((ext_vector_type(8))) short short8;
typedef __attribute__((ext_vector_type(4))) float floatx4;

// ---------------- bf16 helpers (RNE) ----------------
__device__ __forceinline__ unsigned short f2bf(float f) {
  union { float f; uint32_t u; } v; v.f = f;
  uint32_t u = v.u;
  return (unsigned short)((u + 0x7FFFu + ((u >> 16) & 1u)) >> 16);
}
__device__ __forceinline__ float bf2f(unsigned short h) {
  union { uint32_t u; float f; } v; v.u = ((uint32_t)h) << 16;
  return v.f;
}

// ---------------- wave helpers (wave64) ----------------
__device__ __forceinline__ float wsum(float v) {
#pragma unroll
  for (int m = 32; m >= 1; m >>= 1) v += __shfl_xor(v, m, 64);
  return v;
}
__device__ __forceinline__ float wmax(float v) {
#pragma unroll
  for (int m = 32; m >= 1; m >>= 1) v = fmaxf(v, __shfl_xor(v, m, 64));
  return v;
}

__device__ __forceinline__ float gelu_tanh(float x) {
  const float k0 = 0.7978845608028654f;  // sqrt(2/pi)
  float x3 = x * x * x;
  return 0.5f * x * (1.f + tanhf(k0 * (x + 0.044715f * x3)));
}

// ---------------- async global->LDS 16B ----------------
__device__ __forceinline__ void glds16(const unsigned short* g, unsigned short* l) {
  __builtin_amdgcn_global_load_lds((const __attribute__((address_space(1))) void*)g,
                                   (__attribute__((address_space(3))) void*)l, 16, 0, 0);
}

// ---------------- weight transpose + bf16 convert (+ bias concat) ----------------
__global__ __launch_bounds__(256) void convT_all(
    const float* __restrict__ Wq, const float* __restrict__ Wk,
    const float* __restrict__ Wv, const float* __restrict__ Wo,
    const float* __restrict__ W1, const float* __restrict__ W2,
    unsigned short* __restrict__ Wcat_hi, unsigned short* __restrict__ Wcat_lo,
    unsigned short* __restrict__ Wo_t, unsigned short* __restrict__ W1_t,
    unsigned short* __restrict__ W2_t,
    const float* __restrict__ bq, const float* __restrict__ bk,
    const float* __restrict__ bv, float* __restrict__ bias_cat) {
  __shared__ float t[32][33];
  int bid = blockIdx.x;
  int tid = threadIdx.x;
  if (bid >= 3072) {  // bias concat
    for (int i = tid; i < 512; i += 256) {
      bias_cat[i] = bq[i];
      bias_cat[512 + i] = bk[i];
      bias_cat[1024 + i] = bv[i];
    }
    return;
  }
  const float* W;
  unsigned short* hi;
  unsigned short* lo = nullptr;
  int K, N, tix;
  if (bid < 256)       { W = Wq; hi = Wcat_hi;               lo = Wcat_lo;               K = 512;  N = 512;  tix = bid; }
  else if (bid < 512)  { W = Wk; hi = Wcat_hi + 512 * 512;   lo = Wcat_lo + 512 * 512;   K = 512;  N = 512;  tix = bid - 256; }
  else if (bid < 768)  { W = Wv; hi = Wcat_hi + 1024 * 512;  lo = Wcat_lo + 1024 * 512;  K = 512;  N = 512;  tix = bid - 512; }
  else if (bid < 1024) { W = Wo; hi = Wo_t;                  K = 512;  N = 512;  tix = bid - 768; }
  else if (bid < 2048) { W = W1; hi = W1_t;                  K = 512;  N = 2048; tix = bid - 1024; }
  else                 { W = W2; hi = W2_t;                  K = 2048; N = 512;  tix = bid - 2048; }
  int ntn = N >> 5;
  int kt = tix / ntn, nt = tix - kt * ntn;
  int k0 = kt * 32, n0 = nt * 32;
  for (int i = tid; i < 1024; i += 256) {
    int r = i >> 5, c = i & 31;
    t[r][c] = W[(size_t)(k0 + r) * N + n0 + c];
  }
  __syncthreads();
  for (int i = tid; i < 1024; i += 256) {
    int r = i >> 5, c = i & 31;
    float v = t[c][r];
    unsigned short h = f2bf(v);
    size_t oi = (size_t)(n0 + r) * K + k0 + c;
    hi[oi] = h;
    if (lo) lo[oi] = f2bf(v - bf2f(h));
  }
}

// ---------------- LayerNorm -> bf16 (optionally hi+lo split) ----------------
template <int SPLIT>
__global__ __launch_bounds__(256) void ln_kernel(const float* __restrict__ x,
                                                 const float* __restrict__ g,
                                                 const float* __restrict__ be,
                                                 unsigned short* __restrict__ yhi,
                                                 unsigned short* __restrict__ ylo) {
  __shared__ float red[2][4];
  int row = blockIdx.x;
  int tid = threadIdx.x;
  const float* xr = x + (size_t)row * DIMn;
  float2 xv = *(const float2*)(xr + tid * 2);
  float s  = xv.x + xv.y;
  float s2 = xv.x * xv.x + xv.y * xv.y;
  s = wsum(s); s2 = wsum(s2);
  int wv = tid >> 6;
  if ((tid & 63) == 0) { red[0][wv] = s; red[1][wv] = s2; }
  __syncthreads();
  s  = red[0][0] + red[0][1] + red[0][2] + red[0][3];
  s2 = red[1][0] + red[1][1] + red[1][2] + red[1][3];
  float mean = s * (1.f / DIMn);
  float var  = s2 * (1.f / DIMn) - mean * mean;
  float rstd = rsqrtf(var + 1e-6f);
  int d = tid * 2;
  float2 gv = *(const float2*)(g + d);
  float2 bv = *(const float2*)(be + d);
  float o0 = (xv.x - mean) * rstd * gv.x + bv.x;
  float o1 = (xv.y - mean) * rstd * gv.y + bv.y;
  size_t idx = (size_t)row * DIMn + d;
  unsigned short h0 = f2bf(o0), h1 = f2bf(o1);
  ushort2 hv; hv.x = h0; hv.y = h1;
  *(ushort2*)(yhi + idx) = hv;
  if (SPLIT) {
    ushort2 lv; lv.x = f2bf(o0 - bf2f(h0)); lv.y = f2bf(o1 - bf2f(h1));
    *(ushort2*)(ylo + idx) = lv;
  }
}

// ---------------- bf16 MFMA GEMM: C = A @ Bt^T (+bias, EPI, optional split-bf16) ----
template <int BM, int BN, int SPLIT, int EPI, int OUTBF16>
__global__ __launch_bounds__(256) void gemm_mfma(
    const unsigned short* __restrict__ Ahi, const unsigned short* __restrict__ Alo,
    const unsigned short* __restrict__ Bhi, const unsigned short* __restrict__ Blo,
    const float* __restrict__ bias, const float* __restrict__ res,
    void* __restrict__ outp, int M, int N, int K) {
  constexpr int BK = 32;
  constexpr int FI = BM / 32, FJ = BN / 32;
  constexpr int AE = BM * BK, BE = BN * BK;
  __shared__ unsigned short smem[(SPLIT + 1) * (AE + BE)];
  unsigned short* AsHi = smem;
  unsigned short* AsLo = smem + (SPLIT ? AE : 0);
  unsigned short* BsHi = smem + (SPLIT + 1) * AE;
  unsigned short* BsLo = BsHi + (SPLIT ? BE : 0);

  int tid = threadIdx.x;
  int lane = tid & 63;
  int wid = tid >> 6;
  int wm = (wid >> 1) * (BM / 2), wn = (wid & 1) * (BN / 2);
  int bm = blockIdx.y * BM, bn = blockIdx.x * BN;
  int m16 = lane & 15, kg = lane >> 4;

  floatx4 acc[FI][FJ];
#pragma unroll
  for (int i = 0; i < FI; ++i)
#pragma unroll
    for (int j = 0; j < FJ; ++j) { floatx4 z = {0.f, 0.f, 0.f, 0.f}; acc[i][j] = z; }

  const unsigned short* aph = Ahi + (size_t)bm * K;
  const unsigned short* bph = Bhi + (size_t)bn * K;
  const unsigned short* apl = SPLIT ? (Alo + (size_t)bm * K) : nullptr;
  const unsigned short* bpl = SPLIT ? (Blo + (size_t)bn * K) : nullptr;

  for (int k0 = 0; k0 < K; k0 += BK) {
#pragma unroll
    for (int c = tid; c < BM * 4; c += 256) {
      int row = c >> 2, kk = (c & 3) * 8;
      glds16(aph + (size_t)row * K + k0 + kk, AsHi + c * 8);
      if constexpr (SPLIT) glds16(apl + (size_t)row * K + k0 + kk, AsLo + c * 8);
    }
#pragma unroll
    for (int c = tid; c < BN * 4; c += 256) {
      int row = c >> 2, kk = (c & 3) * 8;
      glds16(bph + (size_t)row * K + k0 + kk, BsHi + c * 8);
      if constexpr (SPLIT) glds16(bpl + (size_t)row * K + k0 + kk, BsLo + c * 8);
    }
    __syncthreads();

    short8 ah[FI], bh[FJ];
    short8 al[SPLIT ? FI : 1], bl[SPLIT ? FJ : 1];
#pragma unroll
    for (int i = 0; i < FI; ++i) {
      int r = wm + i * 16 + m16;
      ah[i] = *(const short8*)&AsHi[r * BK + kg * 8];
      if constexpr (SPLIT) al[i] = *(const short8*)&AsLo[r * BK + kg * 8];
    }
#pragma unroll
    for (int j = 0; j < FJ; ++j) {
      int r = wn + j * 16 + m16;
      bh[j] = *(const short8*)&BsHi[r * BK + kg * 8];
      if constexpr (SPLIT) bl[j] = *(const short8*)&BsLo[r * BK + kg * 8];
    }
#pragma unroll
    for (int i = 0; i < FI; ++i)
#pragma unroll
      for (int j = 0; j < FJ; ++j) {
        acc[i][j] = __builtin_amdgcn_mfma_f32_16x16x32_bf16(ah[i], bh[j], acc[i][j], 0, 0, 0);
        if constexpr (SPLIT) {
          acc[i][j] = __builtin_amdgcn_mfma_f32_16x16x32_bf16(al[i], bh[j], acc[i][j], 0, 0, 0);
          acc[i][j] = __builtin_amdgcn_mfma_f32_16x16x32_bf16(ah[i], bl[j], acc[i][j], 0, 0, 0);
        }
      }
    __syncthreads();
  }

#pragma unroll
  for (int i = 0; i < FI; ++i) {
    int gr0 = bm + wm + i * 16 + kg * 4;
#pragma unroll
    for (int j = 0; j < FJ; ++j) {
      int gc = bn + wn + j * 16 + m16;
      float bsv = bias[gc];
#pragma unroll
      for (int r = 0; r < 4; ++r) {
        size_t idx = (size_t)(gr0 + r) * N + gc;
        float v = acc[i][j][r] + bsv;
        if constexpr (EPI == 1) v += res[idx];
        if constexpr (EPI == 2) v = gelu_tanh(v);
        if constexpr (OUTBF16) ((unsigned short*)outp)[idx] = f2bf(v);
        else ((float*)outp)[idx] = v;
      }
    }
  }
}

// ---------------- hash-offset + RoPE + expmap0 (in place in qkv, fp32) -------------
__global__ __launch_bounds__(64) void rope_exp_kernel(float* __restrict__ qkv,
                                                      const float* __restrict__ fcos,
                                                      const float* __restrict__ fsin,
                                                      const float* __restrict__ cvec,
                                                      const float* __restrict__ hash) {
  int lane = threadIdx.x;
  int bid = blockIdx.x;  // ((b*N + n)*NH + h)
  int h = bid & 7;
  int n = (bid >> 3) & (Nn - 1);
  int b = bid >> 13;
  size_t baseq = (size_t)(b * Nn + n) * QKVS + h * HDn;
  size_t basek = baseq + 512;
  int dr = lane & 31;
  float cs = fcos[n * 32 + dr], sn = fsin[n * 32 + dr];
  const float LOG9 = 2.1972245773362196f;

  float qr = qkv[baseq + dr]      + hash[h * HDn + dr] * LOG9;
  float qi = qkv[baseq + dr + 32] + hash[h * HDn + dr + 32] * LOG9;
  float qv = (lane < 32) ? (qr * cs - qi * sn) : (qr * sn + qi * cs);
  float kr = qkv[basek + dr];
  float ki = qkv[basek + dr + 32];
  float kv = (lane < 32) ? (kr * cs - ki * sn) : (kr * sn + ki * cs);

  float c = cvec[b];
  float sqc = sqrtf(c);

  float nq = sqrtf(wsum(qv * qv));
  float nk = sqrtf(wsum(kv * kv));
  float sq = fmaxf(nq, EPSF);
  float sk = fmaxf(nk, EPSF);
  float oq = (nq < EPSF) ? 0.f : (tanhf(sqc * sq) / sqc) * (qv / sq);
  float ok = (nk < EPSF) ? 0.f : (tanhf(sqc * sk) / sqc) * (kv / sk);
  qkv[baseq + lane] = oq;
  qkv[basek + lane] = ok;
}

// ---------------- windowed Poincare attention via MFMA ----------------
// block = (b, h, 32-query tile); S = Q K^T via split-bf16 MFMA, softmax in LDS,
// PV via vectorized VALU (4 queries x 16 lanes x 4 dims).
__global__ __launch_bounds__(256) void attn_mfma(const float* __restrict__ qkv,
                                                 const float* __restrict__ cvec,
                                                 const float* __restrict__ geo,
                                                 unsigned short* __restrict__ attn_out) {
  __shared__ unsigned short Qhi[32][64], Qlo[32][64];
  __shared__ unsigned short Khi[96][64], Klo[96][64];
  __shared__ unsigned short Vs[96][72];
  __shared__ float Sf[32][97];
  __shared__ float x2s[32], y2s[96];

  int tid = threadIdx.x, lane = tid & 63, wv = tid >> 6;
  int bid = blockIdx.x;  // 512 = B*NH*(N/32)
  int nt = bid & 31, h = (bid >> 5) & 7, b = bid >> 8;
  int n0 = nt * 32;
  float c = cvec[b];
  float sqc = sqrtf(c);
  float gs = geo[h];

  // --- stage Q (8 rows/wave): split bf16 + x2 ---
#pragma unroll
  for (int i = 0; i < 8; ++i) {
    int q = wv * 8 + i;
    float qf = qkv[(size_t)(b * Nn + n0 + q) * QKVS + h * HDn + lane];
    unsigned short hh = f2bf(qf);
    Qhi[q][lane] = hh;
    Qlo[q][lane] = f2bf(qf - bf2f(hh));
    float s = wsum(qf * qf);
    if (lane == 0) x2s[q] = s;
  }
  // --- stage K (split bf16 + y2) and V (bf16), 24 rows/wave ---
#pragma unroll 4
  for (int i = 0; i < 24; ++i) {
    int r = wv * 24 + i;
    int gi = n0 - 64 + r;
    float kf = 0.f, vf = 0.f;
    if (gi >= 0) {
      size_t ad = (size_t)(b * Nn + gi) * QKVS + h * HDn + lane;
      kf = qkv[ad + 512];
      vf = qkv[ad + 1024];
    }
    unsigned short hh = f2bf(kf);
    Khi[r][lane] = hh;
    Klo[r][lane] = f2bf(kf - bf2f(hh));
    Vs[r][lane] = f2bf(vf);
    float s = wsum(kf * kf);
    if (lane == 0) y2s[r] = s;
  }
  __syncthreads();

  // --- S = Q K^T via MFMA: M=32 (2 tiles), N=96 (6 tiles), K=64 (2 steps) ---
  int m16 = lane & 15, kg = lane >> 4;
  int mt = wv >> 1;
#pragma unroll
  for (int j = 0; j < 3; ++j) {
    int ntile = (wv & 1) * 3 + j;
    floatx4 acc = {0.f, 0.f, 0.f, 0.f};
#pragma unroll
    for (int ks = 0; ks < 2; ++ks) {
      short8 ah = *(const short8*)&Qhi[mt * 16 + m16][ks * 32 + kg * 8];
      short8 al = *(const short8*)&Qlo[mt * 16 + m16][ks * 32 + kg * 8];
      short8 bh = *(const short8*)&Khi[ntile * 16 + m16][ks * 32 + kg * 8];
      short8 bl = *(const short8*)&Klo[ntile * 16 + m16][ks * 32 + kg * 8];
      acc = __builtin_amdgcn_mfma_f32_16x16x32_bf16(ah, bh, acc, 0, 0, 0);
      acc = __builtin_amdgcn_mfma_f32_16x16x32_bf16(al, bh, acc, 0, 0, 0);
      acc = __builtin_amdgcn_mfma_f32_16x16x32_bf16(ah, bl, acc, 0, 0, 0);
    }
#pragma unroll
    for (int r = 0; r < 4; ++r) Sf[mt * 16 + kg * 4 + r][ntile * 16 + m16] = acc[r];
  }
  __syncthreads();

  // --- scores (fp64 chain) + softmax; w overwrites xy in Sf (own rows only) ---
  for (int i = 0; i < 8; ++i) {
    int nl = wv * 8 + i;
    int r = nl + 1 + lane;  // key row in [1,95]
    float xy = Sf[nl][r];
    float x2 = x2s[nl];
    float y2 = y2s[r];

    double cd = c, xyd = xy, y2d = y2, x2d = x2;
    double alpha = 1.0 - 2.0 * cd * xyd + cd * y2d;
    double beta  = 1.0 - cd * x2d;
    double den = 1.0 - 2.0 * cd * xyd + cd * cd * x2d * y2d;
    den = den > 1e-7 ? den : 1e-7;
    double dn2 = alpha * alpha * x2d - 2.0 * alpha * beta * xyd + beta * beta * y2d;
    dn2 = dn2 > 0.0 ? dn2 : 0.0;
    double dn = sqrt(dn2) / den;
    dn = dn > 1e-7 ? dn : 1e-7;
    double arg = (double)sqc * dn;
    if (arg > 0.9999999) arg = 0.9999999;
    double dist = log((1.0 + arg) / (1.0 - arg)) / (double)sqc;
    float sc = (float)(-(double)gs * dist);

    float mx = wmax(sc);
    float e = expf(sc - mx);
    float se = wsum(e);
    Sf[nl][r] = e / se;
  }
  // no sync needed: PV reads only this wave's own Sf rows (and read-only Vs)

  // --- PV: 4 queries x 16 lanes x 4 dims ---
  int q4 = lane >> 4, dx = (lane & 15) * 4;
#pragma unroll
  for (int qq = 0; qq < 8; qq += 4) {
    int nl = wv * 8 + qq + q4;
    float a0 = 0.f, a1 = 0.f, a2 = 0.f, a3 = 0.f;
#pragma unroll 8
    for (int j = 0; j < 64; ++j) {
      float w = Sf[nl][nl + 1 + j];
      ushort4 vv = *(const ushort4*)&Vs[nl + 1 + j][dx];
      a0 = fmaf(w, bf2f(vv.x), a0);
      a1 = fmaf(w, bf2f(vv.y), a1);
      a2 = fmaf(w, bf2f(vv.z), a2);
      a3 = fmaf(w, bf2f(vv.w), a3);
    }
    size_t o = (size_t)(b * Nn + n0 + nl) * DIMn + h * HDn + dx;
    ushort4 ov;
    ov.x = f2bf(a0); ov.y = f2bf(a1); ov.z = f2bf(a2); ov.w = f2bf(a3);
    *(ushort4*)&attn_out[o] = ov;
  }
}

// ---------------- launcher ----------------
extern "C" void kernel_launch(void* const* d_in, const int* in_sizes, int n_in,
                              void* d_out, int out_size, void* d_ws, size_t ws_size,
                              hipStream_t stream) {
  const float* x    = (const float*)d_in[0];
  const float* fcos = (const float*)d_in[1];
  const float* fsin = (const float*)d_in[2];
  const float* cvec = (const float*)d_in[3];
  const float* Wq = (const float*)d_in[4];  const float* bq = (const float*)d_in[5];
  const float* Wk = (const float*)d_in[6];  const float* bk = (const float*)d_in[7];
  const float* Wv = (const float*)d_in[8];  const float* bv = (const float*)d_in[9];
  const float* Wo = (const float*)d_in[10]; const float* bo = (const float*)d_in[11];
  const float* W1 = (const float*)d_in[12]; const float* b1 = (const float*)d_in[13];
  const float* W2 = (const float*)d_in[14]; const float* b2 = (const float*)d_in[15];
  const float* ln1s = (const float*)d_in[16]; const float* ln1b = (const float*)d_in[17];
  const float* ln2s = (const float*)d_in[18]; const float* ln2b = (const float*)d_in[19];
  const float* geo  = (const float*)d_in[20]; const float* hash = (const float*)d_in[21];
  float* out = (float*)d_out;
  char* base = (char*)d_ws;

  unsigned short* Wcat_hi = (unsigned short*)(base + 0);         // 1536x512 bf16
  unsigned short* Wcat_lo = (unsigned short*)(base + 1572864);
  unsigned short* Wo_t    = (unsigned short*)(base + 3145728);   // 512x512
  unsigned short* W1_t    = (unsigned short*)(base + 3670016);   // 2048x512
  unsigned short* W2_t    = (unsigned short*)(base + 5767168);   // 512x2048
  unsigned short* xn_hi   = (unsigned short*)(base + 7864320);   // 2048x512
  unsigned short* xn_lo   = (unsigned short*)(base + 9961472);
  float*          qkv     = (float*)(base + 12058624);           // 2048x1536 f32
  unsigned short* attnb   = (unsigned short*)(base + 7864320);   // reuse xn_hi
  float*          xout    = (float*)(base + 9961472);            // 2048x512 f32 (reuse)
  unsigned short* hbuf    = (unsigned short*)(base + 14155776);  // 2048x512
  unsigned short* mid     = (unsigned short*)(base + 16252928);  // 2048x2048
  float*          bias_cat= (float*)(base + 24641536);           // 1536 f32

  const int M = Bn * Nn;  // 2048

  convT_all<<<3073, 256, 0, stream>>>(Wq, Wk, Wv, Wo, W1, W2, Wcat_hi, Wcat_lo,
                                      Wo_t, W1_t, W2_t, bq, bk, bv, bias_cat);
  ln_kernel<1><<<M, 256, 0, stream>>>(x, ln1s, ln1b, xn_hi, xn_lo);
  // QKV GEMM, split-bf16, 64x128 tile (grid 12x32 = 384 blocks)
  gemm_mfma<64, 128, 1, 0, 0><<<dim3(QKVS / 128, M / 64), 256, 0, stream>>>(
      xn_hi, xn_lo, Wcat_hi, Wcat_lo, bias_cat, nullptr, qkv, M, QKVS, 512);
  rope_exp_kernel<<<Bn * Nn * NHn, 64, 0, stream>>>(qkv, fcos, fsin, cvec, hash);
  attn_mfma<<<Bn * NHn * (Nn / 32), 256, 0, stream>>>(qkv, cvec, geo, attnb);
  gemm_mfma<64, 64, 0, 1, 0><<<dim3(DIMn / 64, M / 64), 256, 0, stream>>>(
      attnb, nullptr, Wo_t, nullptr, bo, x, xout, M, DIMn, 512);
  ln_kernel<0><<<M, 256, 0, stream>>>(xout, ln2s, ln2b, hbuf, nullptr);
  gemm_mfma<128, 128, 0, 2, 1><<<dim3(2048 / 128, M / 128), 256, 0, stream>>>(
      hbuf, nullptr, W1_t, nullptr, b1, nullptr, mid, M, 2048, 512);
  gemm_mfma<64, 64, 0, 1, 0><<<dim3(DIMn / 64, M / 64), 256, 0, stream>>>(
      mid, nullptr, W2_t, nullptr, b2, xout, out, M, DIMn, 2048);
}

// Round 4
// 213.700 us; speedup vs baseline: 2.1012x; 1.0652x over previous
//
#include <hip/hip_runtime.h>
#include <math.h>
#include <stdint.h>

#define Bn   2
#define Nn   1024
#define DIMn 512
#define NHn  8
#define HDn  64
#define QKVS 1536
#define EPSF 1e-7f

typedef __attribute__((ext_vector_type(8))) short short8;
typedef __attribute__((ext_vector_type(4))) float floatx4;

// ---------------- bf16 helpers (RNE) ----------------
__device__ __forceinline__ unsigned short f2bf(float f) {
  union { float f; uint32_t u; } v; v.f = f;
  uint32_t u = v.u;
  return (unsigned short)((u + 0x7FFFu + ((u >> 16) & 1u)) >> 16);
}
__device__ __forceinline__ float bf2f(unsigned short h) {
  union { uint32_t u; float f; } v; v.u = ((uint32_t)h) << 16;
  return v.f;
}

// ---------------- wave helpers (wave64) ----------------
__device__ __forceinline__ float wsum(float v) {
#pragma unroll
  for (int m = 32; m >= 1; m >>= 1) v += __shfl_xor(v, m, 64);
  return v;
}
__device__ __forceinline__ float wmax(float v) {
#pragma unroll
  for (int m = 32; m >= 1; m >>= 1) v = fmaxf(v, __shfl_xor(v, m, 64));
  return v;
}

__device__ __forceinline__ float gelu_tanh(float x) {
  const float k0 = 0.7978845608028654f;  // sqrt(2/pi)
  float x3 = x * x * x;
  return 0.5f * x * (1.f + tanhf(k0 * (x + 0.044715f * x3)));
}

// ---------------- async global->LDS 16B ----------------
__device__ __forceinline__ void glds16(const unsigned short* g, unsigned short* l) {
  __builtin_amdgcn_global_load_lds((const __attribute__((address_space(1))) void*)g,
                                   (__attribute__((address_space(3))) void*)l, 16, 0, 0);
}

// ---------------- weight transpose + bf16 convert (+ bias concat) ----------------
__global__ __launch_bounds__(256) void convT_all(
    const float* __restrict__ Wq, const float* __restrict__ Wk,
    const float* __restrict__ Wv, const float* __restrict__ Wo,
    const float* __restrict__ W1, const float* __restrict__ W2,
    unsigned short* __restrict__ Wcat_hi, unsigned short* __restrict__ Wcat_lo,
    unsigned short* __restrict__ Wo_t, unsigned short* __restrict__ W1_t,
    unsigned short* __restrict__ W2_t,
    const float* __restrict__ bq, const float* __restrict__ bk,
    const float* __restrict__ bv, float* __restrict__ bias_cat) {
  __shared__ float t[32][33];
  int bid = blockIdx.x;
  int tid = threadIdx.x;
  if (bid >= 3072) {  // bias concat
    for (int i = tid; i < 512; i += 256) {
      bias_cat[i] = bq[i];
      bias_cat[512 + i] = bk[i];
      bias_cat[1024 + i] = bv[i];
    }
    return;
  }
  const float* W;
  unsigned short* hi;
  unsigned short* lo = nullptr;
  int K, N, tix;
  if (bid < 256)       { W = Wq; hi = Wcat_hi;               lo = Wcat_lo;               K = 512;  N = 512;  tix = bid; }
  else if (bid < 512)  { W = Wk; hi = Wcat_hi + 512 * 512;   lo = Wcat_lo + 512 * 512;   K = 512;  N = 512;  tix = bid - 256; }
  else if (bid < 768)  { W = Wv; hi = Wcat_hi + 1024 * 512;  K = 512;  N = 512;  tix = bid - 512; }
  else if (bid < 1024) { W = Wo; hi = Wo_t;                  K = 512;  N = 512;  tix = bid - 768; }
  else if (bid < 2048) { W = W1; hi = W1_t;                  K = 512;  N = 2048; tix = bid - 1024; }
  else                 { W = W2; hi = W2_t;                  K = 2048; N = 512;  tix = bid - 2048; }
  int ntn = N >> 5;
  int kt = tix / ntn, nt = tix - kt * ntn;
  int k0 = kt * 32, n0 = nt * 32;
  for (int i = tid; i < 1024; i += 256) {
    int r = i >> 5, c = i & 31;
    t[r][c] = W[(size_t)(k0 + r) * N + n0 + c];
  }
  __syncthreads();
  for (int i = tid; i < 1024; i += 256) {
    int r = i >> 5, c = i & 31;
    float v = t[c][r];
    unsigned short h = f2bf(v);
    size_t oi = (size_t)(n0 + r) * K + k0 + c;
    hi[oi] = h;
    if (lo) lo[oi] = f2bf(v - bf2f(h));
  }
}

// ---------------- LayerNorm -> bf16 (optionally hi+lo split) ----------------
template <int SPLIT>
__global__ __launch_bounds__(256) void ln_kernel(const float* __restrict__ x,
                                                 const float* __restrict__ g,
                                                 const float* __restrict__ be,
                                                 unsigned short* __restrict__ yhi,
                                                 unsigned short* __restrict__ ylo) {
  __shared__ float red[2][4];
  int row = blockIdx.x;
  int tid = threadIdx.x;
  const float* xr = x + (size_t)row * DIMn;
  float2 xv = *(const float2*)(xr + tid * 2);
  float s  = xv.x + xv.y;
  float s2 = xv.x * xv.x + xv.y * xv.y;
  s = wsum(s); s2 = wsum(s2);
  int wv = tid >> 6;
  if ((tid & 63) == 0) { red[0][wv] = s; red[1][wv] = s2; }
  __syncthreads();
  s  = red[0][0] + red[0][1] + red[0][2] + red[0][3];
  s2 = red[1][0] + red[1][1] + red[1][2] + red[1][3];
  float mean = s * (1.f / DIMn);
  float var  = s2 * (1.f / DIMn) - mean * mean;
  float rstd = rsqrtf(var + 1e-6f);
  int d = tid * 2;
  float2 gv = *(const float2*)(g + d);
  float2 bv = *(const float2*)(be + d);
  float o0 = (xv.x - mean) * rstd * gv.x + bv.x;
  float o1 = (xv.y - mean) * rstd * gv.y + bv.y;
  size_t idx = (size_t)row * DIMn + d;
  unsigned short h0 = f2bf(o0), h1 = f2bf(o1);
  ushort2 hv; hv.x = h0; hv.y = h1;
  *(ushort2*)(yhi + idx) = hv;
  if (SPLIT) {
    ushort2 lv; lv.x = f2bf(o0 - bf2f(h0)); lv.y = f2bf(o1 - bf2f(h1));
    *(ushort2*)(ylo + idx) = lv;
  }
}

// ---------------- bf16 MFMA GEMM: C = A @ Bt^T ----------------
// SPLIT: 0=plain, 1=full split-bf16, 2=hybrid (split only where bn<1024).
// EPI: 0=bias, 1=bias+res, 2=bias+gelu.
template <int BM, int BN, int BKT, int SPLIT, int EPI, int OUTBF16>
__global__ __launch_bounds__(256) void gemm_mfma(
    const unsigned short* __restrict__ Ahi, const unsigned short* __restrict__ Alo,
    const unsigned short* __restrict__ Bhi, const unsigned short* __restrict__ Blo,
    const float* __restrict__ bias, const float* __restrict__ res,
    void* __restrict__ outp, int M, int N, int K) {
  constexpr int FI = BM / 32, FJ = BN / 32;
  constexpr int AE = BM * BKT, BE = BN * BKT;
  constexpr int NB = (SPLIT > 0) ? 2 : 1;
  constexpr int CPR = BKT / 8;   // 16B chunks per row
  constexpr int ACH = BM * CPR, BCH = BN * CPR;
  __shared__ unsigned short smem[NB * (AE + BE)];
  unsigned short* AsHi = smem;
  unsigned short* AsLo = smem + ((SPLIT > 0) ? AE : 0);
  unsigned short* BsHi = smem + NB * AE;
  unsigned short* BsLo = BsHi + ((SPLIT > 0) ? BE : 0);

  int tid = threadIdx.x;
  int lane = tid & 63;
  int wid = tid >> 6;
  int wm = (wid >> 1) * (BM / 2), wn = (wid & 1) * (BN / 2);
  int bm = blockIdx.y * BM, bn = blockIdx.x * BN;
  int m16 = lane & 15, kg = lane >> 4;
  bool dos = (SPLIT == 1) || (SPLIT == 2 && bn < 1024);

  floatx4 acc[FI][FJ];
#pragma unroll
  for (int i = 0; i < FI; ++i)
#pragma unroll
    for (int j = 0; j < FJ; ++j) { floatx4 z = {0.f, 0.f, 0.f, 0.f}; acc[i][j] = z; }

  const unsigned short* aph = Ahi + (size_t)bm * K;
  const unsigned short* bph = Bhi + (size_t)bn * K;
  const unsigned short* apl = (SPLIT > 0) ? (Alo + (size_t)bm * K) : nullptr;
  const unsigned short* bpl = (SPLIT > 0) ? (Blo + (size_t)bn * K) : nullptr;

  for (int k0 = 0; k0 < K; k0 += BKT) {
#pragma unroll
    for (int c = tid; c < ACH; c += 256) {
      int row = c / CPR, kk = (c % CPR) * 8;
      glds16(aph + (size_t)row * K + k0 + kk, AsHi + c * 8);
      if (SPLIT > 0 && dos) glds16(apl + (size_t)row * K + k0 + kk, AsLo + c * 8);
    }
#pragma unroll
    for (int c = tid; c < BCH; c += 256) {
      int row = c / CPR, kk = (c % CPR) * 8;
      glds16(bph + (size_t)row * K + k0 + kk, BsHi + c * 8);
      if (SPLIT > 0 && dos) glds16(bpl + (size_t)row * K + k0 + kk, BsLo + c * 8);
    }
    __syncthreads();

#pragma unroll
    for (int ks = 0; ks < BKT / 32; ++ks) {
      short8 ah[FI], bh[FJ];
      short8 al[(SPLIT > 0) ? FI : 1], bl[(SPLIT > 0) ? FJ : 1];
#pragma unroll
      for (int i = 0; i < FI; ++i) {
        int r = wm + i * 16 + m16;
        ah[i] = *(const short8*)&AsHi[r * BKT + ks * 32 + kg * 8];
        if (SPLIT > 0 && dos) al[i] = *(const short8*)&AsLo[r * BKT + ks * 32 + kg * 8];
      }
#pragma unroll
      for (int j = 0; j < FJ; ++j) {
        int r = wn + j * 16 + m16;
        bh[j] = *(const short8*)&BsHi[r * BKT + ks * 32 + kg * 8];
        if (SPLIT > 0 && dos) bl[j] = *(const short8*)&BsLo[r * BKT + ks * 32 + kg * 8];
      }
#pragma unroll
      for (int i = 0; i < FI; ++i)
#pragma unroll
        for (int j = 0; j < FJ; ++j) {
          acc[i][j] = __builtin_amdgcn_mfma_f32_16x16x32_bf16(ah[i], bh[j], acc[i][j], 0, 0, 0);
          if (SPLIT > 0) {
            if (dos) {
              acc[i][j] = __builtin_amdgcn_mfma_f32_16x16x32_bf16(al[i], bh[j], acc[i][j], 0, 0, 0);
              acc[i][j] = __builtin_amdgcn_mfma_f32_16x16x32_bf16(ah[i], bl[j], acc[i][j], 0, 0, 0);
            }
          }
        }
    }
    __syncthreads();
  }

  // epilogue: C/D map col=lane&15, row=(lane>>4)*4+reg
#pragma unroll
  for (int i = 0; i < FI; ++i) {
    int gr0 = bm + wm + i * 16 + kg * 4;
#pragma unroll
    for (int j = 0; j < FJ; ++j) {
      int gc = bn + wn + j * 16 + m16;
      float bsv = bias[gc];
#pragma unroll
      for (int r = 0; r < 4; ++r) {
        size_t idx = (size_t)(gr0 + r) * N + gc;
        float v = acc[i][j][r] + bsv;
        if constexpr (EPI == 1) v += res[idx];
        if constexpr (EPI == 2) v = gelu_tanh(v);
        if constexpr (OUTBF16) ((unsigned short*)outp)[idx] = f2bf(v);
        else ((float*)outp)[idx] = v;
      }
    }
  }
}

// ---------------- fused hash+RoPE+expmap0 + windowed Poincare attention ----------------
// block = (b, h, 32-query tile). Reads RAW qkv; applies hash/rope/expmap during staging.
__global__ __launch_bounds__(256) void attn_fused(const float* __restrict__ qkv,
                                                  const float* __restrict__ fcos,
                                                  const float* __restrict__ fsin,
                                                  const float* __restrict__ cvec,
                                                  const float* __restrict__ geo,
                                                  const float* __restrict__ hash,
                                                  unsigned short* __restrict__ attn_out) {
  __shared__ unsigned short Qhi[32][64], Qlo[32][64];
  __shared__ unsigned short Khi[96][64], Klo[96][64];
  __shared__ unsigned short Vs[96][72];
  __shared__ float Sf[32][97];
  __shared__ float x2s[32], y2s[96];

  int tid = threadIdx.x, lane = tid & 63, wv = tid >> 6;
  int bid = blockIdx.x;  // 512 = B*NH*(N/32)
  int nt = bid & 31, h = (bid >> 5) & 7, b = bid >> 8;
  int n0 = nt * 32;
  float c = cvec[b];
  float sqc = sqrtf(c);
  float gs = geo[h];
  int dr = lane & 31;
  bool hih = lane >= 32;
  const float LOG9 = 2.1972245773362196f;
  float hofr = hash[h * HDn + dr] * LOG9;
  float hofi = hash[h * HDn + dr + 32] * LOG9;

  // --- stage Q (8 rows/wave): hash + rope + expmap0, split bf16 + x2 ---
#pragma unroll
  for (int i = 0; i < 8; ++i) {
    int q = wv * 8 + i;
    int n = n0 + q;
    size_t bas = (size_t)(b * Nn + n) * QKVS + h * HDn;
    float qr = qkv[bas + dr] + hofr;
    float qi = qkv[bas + dr + 32] + hofi;
    float cs = fcos[n * 32 + dr], sn = fsin[n * 32 + dr];
    float qv = hih ? (qr * sn + qi * cs) : (qr * cs - qi * sn);
    float nq = sqrtf(wsum(qv * qv));
    float sq = fmaxf(nq, EPSF);
    float mag = tanhf(sqc * sq) / sqc;
    float oq = (nq < EPSF) ? 0.f : mag * (qv / sq);
    unsigned short hh = f2bf(oq);
    Qhi[q][lane] = hh;
    Qlo[q][lane] = f2bf(oq - bf2f(hh));
    if (lane == 0) x2s[q] = (nq < EPSF) ? 0.f : mag * mag;
  }
  // --- stage K (rope + expmap0, split bf16 + y2) and V (bf16), 24 rows/wave ---
#pragma unroll 4
  for (int i = 0; i < 24; ++i) {
    int r = wv * 24 + i;
    int gi = n0 - 64 + r;
    float ok = 0.f, vf = 0.f, y2 = 0.f;
    if (gi >= 0) {
      size_t bas = (size_t)(b * Nn + gi) * QKVS + h * HDn;
      float kr = qkv[bas + 512 + dr];
      float ki = qkv[bas + 512 + dr + 32];
      vf = qkv[bas + 1024 + lane];
      float cs = fcos[gi * 32 + dr], sn = fsin[gi * 32 + dr];
      float kv = hih ? (kr * sn + ki * cs) : (kr * cs - ki * sn);
      float nk = sqrtf(wsum(kv * kv));
      float sk = fmaxf(nk, EPSF);
      float mag = tanhf(sqc * sk) / sqc;
      ok = (nk < EPSF) ? 0.f : mag * (kv / sk);
      y2 = (nk < EPSF) ? 0.f : mag * mag;
    }
    unsigned short hh = f2bf(ok);
    Khi[r][lane] = hh;
    Klo[r][lane] = f2bf(ok - bf2f(hh));
    Vs[r][lane] = f2bf(vf);
    if (lane == 0) y2s[r] = y2;
  }
  __syncthreads();

  // --- S = Q K^T via split-bf16 MFMA: M=32 (2 tiles), N=96 (6 tiles), K=64 ---
  int m16 = lane & 15, kg = lane >> 4;
  int mt = wv >> 1;
#pragma unroll
  for (int j = 0; j < 3; ++j) {
    int ntile = (wv & 1) * 3 + j;
    floatx4 acc = {0.f, 0.f, 0.f, 0.f};
#pragma unroll
    for (int ks = 0; ks < 2; ++ks) {
      short8 ah = *(const short8*)&Qhi[mt * 16 + m16][ks * 32 + kg * 8];
      short8 al = *(const short8*)&Qlo[mt * 16 + m16][ks * 32 + kg * 8];
      short8 bh = *(const short8*)&Khi[ntile * 16 + m16][ks * 32 + kg * 8];
      short8 bl = *(const short8*)&Klo[ntile * 16 + m16][ks * 32 + kg * 8];
      acc = __builtin_amdgcn_mfma_f32_16x16x32_bf16(ah, bh, acc, 0, 0, 0);
      acc = __builtin_amdgcn_mfma_f32_16x16x32_bf16(al, bh, acc, 0, 0, 0);
      acc = __builtin_amdgcn_mfma_f32_16x16x32_bf16(ah, bl, acc, 0, 0, 0);
    }
#pragma unroll
    for (int r = 0; r < 4; ++r) Sf[mt * 16 + kg * 4 + r][ntile * 16 + m16] = acc[r];
  }
  __syncthreads();

  // --- scores (fp64 chain) + softmax; w overwrites xy in Sf (own rows only) ---
  for (int i = 0; i < 8; ++i) {
    int nl = wv * 8 + i;
    int r = nl + 1 + lane;  // key row in [1,95]
    float xy = Sf[nl][r];
    float x2 = x2s[nl];
    float y2 = y2s[r];

    double cd = c, xyd = xy, y2d = y2, x2d = x2;
    double alpha = 1.0 - 2.0 * cd * xyd + cd * y2d;
    double beta  = 1.0 - cd * x2d;
    double den = 1.0 - 2.0 * cd * xyd + cd * cd * x2d * y2d;
    den = den > 1e-7 ? den : 1e-7;
    double dn2 = alpha * alpha * x2d - 2.0 * alpha * beta * xyd + beta * beta * y2d;
    dn2 = dn2 > 0.0 ? dn2 : 0.0;
    double dn = sqrt(dn2) / den;
    dn = dn > 1e-7 ? dn : 1e-7;
    double arg = (double)sqc * dn;
    if (arg > 0.9999999) arg = 0.9999999;
    double dist = log((1.0 + arg) / (1.0 - arg)) / (double)sqc;
    float sc = (float)(-(double)gs * dist);

    float mx = wmax(sc);
    float e = expf(sc - mx);
    float se = wsum(e);
    Sf[nl][r] = e / se;
  }
  // no sync needed: PV reads only this wave's own Sf rows (and read-only Vs)

  // --- PV: 4 queries x 16 lanes x 4 dims ---
  int q4 = lane >> 4, dx = (lane & 15) * 4;
#pragma unroll
  for (int qq = 0; qq < 8; qq += 4) {
    int nl = wv * 8 + qq + q4;
    float a0 = 0.f, a1 = 0.f, a2 = 0.f, a3 = 0.f;
#pragma unroll 8
    for (int j = 0; j < 64; ++j) {
      float w = Sf[nl][nl + 1 + j];
      ushort4 vv = *(const ushort4*)&Vs[nl + 1 + j][dx];
      a0 = fmaf(w, bf2f(vv.x), a0);
      a1 = fmaf(w, bf2f(vv.y), a1);
      a2 = fmaf(w, bf2f(vv.z), a2);
      a3 = fmaf(w, bf2f(vv.w), a3);
    }
    size_t o = (size_t)(b * Nn + n0 + nl) * DIMn + h * HDn + dx;
    ushort4 ov;
    ov.x = f2bf(a0); ov.y = f2bf(a1); ov.z = f2bf(a2); ov.w = f2bf(a3);
    *(ushort4*)&attn_out[o] = ov;
  }
}

// ---------------- launcher ----------------
extern "C" void kernel_launch(void* const* d_in, const int* in_sizes, int n_in,
                              void* d_out, int out_size, void* d_ws, size_t ws_size,
                              hipStream_t stream) {
  const float* x    = (const float*)d_in[0];
  const float* fcos = (const float*)d_in[1];
  const float* fsin = (const float*)d_in[2];
  const float* cvec = (const float*)d_in[3];
  const float* Wq = (const float*)d_in[4];  const float* bq = (const float*)d_in[5];
  const float* Wk = (const float*)d_in[6];  const float* bk = (const float*)d_in[7];
  const float* Wv = (const float*)d_in[8];  const float* bv = (const float*)d_in[9];
  const float* Wo = (const float*)d_in[10]; const float* bo = (const float*)d_in[11];
  const float* W1 = (const float*)d_in[12]; const float* b1 = (const float*)d_in[13];
  const float* W2 = (const float*)d_in[14]; const float* b2 = (const float*)d_in[15];
  const float* ln1s = (const float*)d_in[16]; const float* ln1b = (const float*)d_in[17];
  const float* ln2s = (const float*)d_in[18]; const float* ln2b = (const float*)d_in[19];
  const float* geo  = (const float*)d_in[20]; const float* hash = (const float*)d_in[21];
  float* out = (float*)d_out;
  char* base = (char*)d_ws;

  unsigned short* Wcat_hi = (unsigned short*)(base + 0);         // 1536x512 bf16
  unsigned short* Wcat_lo = (unsigned short*)(base + 1572864);
  unsigned short* Wo_t    = (unsigned short*)(base + 3145728);   // 512x512
  unsigned short* W1_t    = (unsigned short*)(base + 3670016);   // 2048x512
  unsigned short* W2_t    = (unsigned short*)(base + 5767168);   // 512x2048
  unsigned short* xn_hi   = (unsigned short*)(base + 7864320);   // 2048x512
  unsigned short* xn_lo   = (unsigned short*)(base + 9961472);
  float*          qkv     = (float*)(base + 12058624);           // 2048x1536 f32
  unsigned short* attnb   = (unsigned short*)(base + 7864320);   // reuse xn_hi
  float*          xout    = (float*)(base + 9961472);            // 2048x512 f32 (reuse)
  unsigned short* hbuf    = (unsigned short*)(base + 14155776);  // 2048x512
  unsigned short* mid     = (unsigned short*)(base + 16252928);  // 2048x2048
  float*          bias_cat= (float*)(base + 24641536);           // 1536 f32

  const int M = Bn * Nn;  // 2048

  convT_all<<<3073, 256, 0, stream>>>(Wq, Wk, Wv, Wo, W1, W2, Wcat_hi, Wcat_lo,
                                      Wo_t, W1_t, W2_t, bq, bk, bv, bias_cat);
  ln_kernel<1><<<M, 256, 0, stream>>>(x, ln1s, ln1b, xn_hi, xn_lo);
  // QKV GEMM, hybrid split (q,k split / v plain), 64x64 tile -> grid 24x32 = 768
  gemm_mfma<64, 64, 32, 2, 0, 0><<<dim3(QKVS / 64, M / 64), 256, 0, stream>>>(
      xn_hi, xn_lo, Wcat_hi, Wcat_lo, bias_cat, nullptr, qkv, M, QKVS, 512);
  // fused rope + windowed Poincare attention -> attnb bf16 [M][512]
  attn_fused<<<Bn * NHn * (Nn / 32), 256, 0, stream>>>(qkv, fcos, fsin, cvec, geo, hash, attnb);
  // Wo + residual(x) -> xout f32; 32x64 tile, BK=64 -> grid 8x64 = 512
  gemm_mfma<32, 64, 64, 0, 1, 0><<<dim3(DIMn / 64, M / 32), 256, 0, stream>>>(
      attnb, nullptr, Wo_t, nullptr, bo, x, xout, M, DIMn, 512);
  ln_kernel<0><<<M, 256, 0, stream>>>(xout, ln2s, ln2b, hbuf, nullptr);
  // FFN1 + gelu -> mid bf16; 64x128 tile, BK=64 -> grid 16x32 = 512
  gemm_mfma<64, 128, 64, 0, 2, 1><<<dim3(2048 / 128, M / 64), 256, 0, stream>>>(
      hbuf, nullptr, W1_t, nullptr, b1, nullptr, mid, M, 2048, 512);
  // FFN2 + residual(xout) -> out f32; 32x64 tile, BK=64 -> grid 8x64 = 512
  gemm_mfma<32, 64, 64, 0, 1, 0><<<dim3(DIMn / 64, M / 32), 256, 0, stream>>>(
      mid, nullptr, W2_t, nullptr, b2, xout, out, M, DIMn, 2048);
}

// Round 5
// 208.971 us; speedup vs baseline: 2.1487x; 1.0226x over previous
//
#include <hip/hip_runtime.h>
#include <math.h>
#include <stdint.h>

#define Bn   2
#define Nn   1024
#define DIMn 512
#define NHn  8
#define HDn  64
#define QKVS 1536
#define EPSF 1e-7f

typedef __attribute__((ext_vector_type(8))) short short8;
typedef __attribute__((ext_vector_type(4))) float floatx4;

// ---------------- bf16 helpers (RNE) ----------------
__device__ __forceinline__ unsigned short f2bf(float f) {
  union { float f; uint32_t u; } v; v.f = f;
  uint32_t u = v.u;
  return (unsigned short)((u + 0x7FFFu + ((u >> 16) & 1u)) >> 16);
}
__device__ __forceinline__ float bf2f(unsigned short h) {
  union { uint32_t u; float f; } v; v.u = ((uint32_t)h) << 16;
  return v.f;
}

// ---------------- wave helpers (wave64) ----------------
__device__ __forceinline__ float wsum(float v) {
#pragma unroll
  for (int m = 32; m >= 1; m >>= 1) v += __shfl_xor(v, m, 64);
  return v;
}
__device__ __forceinline__ float wmax(float v) {
#pragma unroll
  for (int m = 32; m >= 1; m >>= 1) v = fmaxf(v, __shfl_xor(v, m, 64));
  return v;
}

__device__ __forceinline__ float gelu_tanh(float x) {
  const float k0 = 0.7978845608028654f;  // sqrt(2/pi)
  float x3 = x * x * x;
  return 0.5f * x * (1.f + tanhf(k0 * (x + 0.044715f * x3)));
}

// ---------------- async global->LDS 16B ----------------
__device__ __forceinline__ void glds16(const unsigned short* g, unsigned short* l) {
  __builtin_amdgcn_global_load_lds((const __attribute__((address_space(1))) void*)g,
                                   (__attribute__((address_space(3))) void*)l, 16, 0, 0);
}

// ---------------- weight transpose + bf16 convert (+ bias concat) ----------------
__global__ __launch_bounds__(256) void convT_all(
    const float* __restrict__ Wq, const float* __restrict__ Wk,
    const float* __restrict__ Wv, const float* __restrict__ Wo,
    const float* __restrict__ W1, const float* __restrict__ W2,
    unsigned short* __restrict__ Wcat_hi, unsigned short* __restrict__ Wcat_lo,
    unsigned short* __restrict__ Wo_t, unsigned short* __restrict__ W1_t,
    unsigned short* __restrict__ W2_t,
    const float* __restrict__ bq, const float* __restrict__ bk,
    const float* __restrict__ bv, float* __restrict__ bias_cat) {
  __shared__ float t[32][33];
  int bid = blockIdx.x;
  int tid = threadIdx.x;
  if (bid >= 3072) {  // bias concat
    for (int i = tid; i < 512; i += 256) {
      bias_cat[i] = bq[i];
      bias_cat[512 + i] = bk[i];
      bias_cat[1024 + i] = bv[i];
    }
    return;
  }
  const float* W;
  unsigned short* hi;
  unsigned short* lo = nullptr;
  int K, N, tix;
  if (bid < 256)       { W = Wq; hi = Wcat_hi;               lo = Wcat_lo;               K = 512;  N = 512;  tix = bid; }
  else if (bid < 512)  { W = Wk; hi = Wcat_hi + 512 * 512;   lo = Wcat_lo + 512 * 512;   K = 512;  N = 512;  tix = bid - 256; }
  else if (bid < 768)  { W = Wv; hi = Wcat_hi + 1024 * 512;  K = 512;  N = 512;  tix = bid - 512; }
  else if (bid < 1024) { W = Wo; hi = Wo_t;                  K = 512;  N = 512;  tix = bid - 768; }
  else if (bid < 2048) { W = W1; hi = W1_t;                  K = 512;  N = 2048; tix = bid - 1024; }
  else                 { W = W2; hi = W2_t;                  K = 2048; N = 512;  tix = bid - 2048; }
  int ntn = N >> 5;
  int kt = tix / ntn, nt = tix - kt * ntn;
  int k0 = kt * 32, n0 = nt * 32;
  for (int i = tid; i < 1024; i += 256) {
    int r = i >> 5, c = i & 31;
    t[r][c] = W[(size_t)(k0 + r) * N + n0 + c];
  }
  __syncthreads();
  for (int i = tid; i < 1024; i += 256) {
    int r = i >> 5, c = i & 31;
    float v = t[c][r];
    unsigned short h = f2bf(v);
    size_t oi = (size_t)(n0 + r) * K + k0 + c;
    hi[oi] = h;
    if (lo) lo[oi] = f2bf(v - bf2f(h));
  }
}

// ---------------- LayerNorm -> bf16 (optionally hi+lo split) ----------------
template <int SPLIT>
__global__ __launch_bounds__(256) void ln_kernel(const float* __restrict__ x,
                                                 const float* __restrict__ g,
                                                 const float* __restrict__ be,
                                                 unsigned short* __restrict__ yhi,
                                                 unsigned short* __restrict__ ylo) {
  __shared__ float red[2][4];
  int row = blockIdx.x;
  int tid = threadIdx.x;
  const float* xr = x + (size_t)row * DIMn;
  float2 xv = *(const float2*)(xr + tid * 2);
  float s  = xv.x + xv.y;
  float s2 = xv.x * xv.x + xv.y * xv.y;
  s = wsum(s); s2 = wsum(s2);
  int wv = tid >> 6;
  if ((tid & 63) == 0) { red[0][wv] = s; red[1][wv] = s2; }
  __syncthreads();
  s  = red[0][0] + red[0][1] + red[0][2] + red[0][3];
  s2 = red[1][0] + red[1][1] + red[1][2] + red[1][3];
  float mean = s * (1.f / DIMn);
  float var  = s2 * (1.f / DIMn) - mean * mean;
  float rstd = rsqrtf(var + 1e-6f);
  int d = tid * 2;
  float2 gv = *(const float2*)(g + d);
  float2 bv = *(const float2*)(be + d);
  float o0 = (xv.x - mean) * rstd * gv.x + bv.x;
  float o1 = (xv.y - mean) * rstd * gv.y + bv.y;
  size_t idx = (size_t)row * DIMn + d;
  unsigned short h0 = f2bf(o0), h1 = f2bf(o1);
  ushort2 hv; hv.x = h0; hv.y = h1;
  *(ushort2*)(yhi + idx) = hv;
  if (SPLIT) {
    ushort2 lv; lv.x = f2bf(o0 - bf2f(h0)); lv.y = f2bf(o1 - bf2f(h1));
    *(ushort2*)(ylo + idx) = lv;
  }
}

// ---------------- bf16 MFMA GEMM: C = A @ Bt^T ----------------
// SPLIT: 0=plain, 1=full split-bf16, 2=hybrid (split only where bn<1024).
// EPI: 0=bias, 1=bias+res, 2=bias+gelu.
template <int BM, int BN, int BKT, int SPLIT, int EPI, int OUTBF16>
__global__ __launch_bounds__(256) void gemm_mfma(
    const unsigned short* __restrict__ Ahi, const unsigned short* __restrict__ Alo,
    const unsigned short* __restrict__ Bhi, const unsigned short* __restrict__ Blo,
    const float* __restrict__ bias, const float* __restrict__ res,
    void* __restrict__ outp, int M, int N, int K) {
  constexpr int FI = BM / 32, FJ = BN / 32;
  constexpr int AE = BM * BKT, BE = BN * BKT;
  constexpr int NB = (SPLIT > 0) ? 2 : 1;
  constexpr int CPR = BKT / 8;   // 16B chunks per row
  constexpr int ACH = BM * CPR, BCH = BN * CPR;
  __shared__ unsigned short smem[NB * (AE + BE)];
  unsigned short* AsHi = smem;
  unsigned short* AsLo = smem + ((SPLIT > 0) ? AE : 0);
  unsigned short* BsHi = smem + NB * AE;
  unsigned short* BsLo = BsHi + ((SPLIT > 0) ? BE : 0);

  int tid = threadIdx.x;
  int lane = tid & 63;
  int wid = tid >> 6;
  int wm = (wid >> 1) * (BM / 2), wn = (wid & 1) * (BN / 2);
  int bm = blockIdx.y * BM, bn = blockIdx.x * BN;
  int m16 = lane & 15, kg = lane >> 4;
  bool dos = (SPLIT == 1) || (SPLIT == 2 && bn < 1024);

  floatx4 acc[FI][FJ];
#pragma unroll
  for (int i = 0; i < FI; ++i)
#pragma unroll
    for (int j = 0; j < FJ; ++j) { floatx4 z = {0.f, 0.f, 0.f, 0.f}; acc[i][j] = z; }

  const unsigned short* aph = Ahi + (size_t)bm * K;
  const unsigned short* bph = Bhi + (size_t)bn * K;
  const unsigned short* apl = (SPLIT > 0) ? (Alo + (size_t)bm * K) : nullptr;
  const unsigned short* bpl = (SPLIT > 0) ? (Blo + (size_t)bn * K) : nullptr;

  for (int k0 = 0; k0 < K; k0 += BKT) {
#pragma unroll
    for (int c = tid; c < ACH; c += 256) {
      int row = c / CPR, kk = (c % CPR) * 8;
      glds16(aph + (size_t)row * K + k0 + kk, AsHi + c * 8);
      if (SPLIT > 0 && dos) glds16(apl + (size_t)row * K + k0 + kk, AsLo + c * 8);
    }
#pragma unroll
    for (int c = tid; c < BCH; c += 256) {
      int row = c / CPR, kk = (c % CPR) * 8;
      glds16(bph + (size_t)row * K + k0 + kk, BsHi + c * 8);
      if (SPLIT > 0 && dos) glds16(bpl + (size_t)row * K + k0 + kk, BsLo + c * 8);
    }
    __syncthreads();

#pragma unroll
    for (int ks = 0; ks < BKT / 32; ++ks) {
      short8 ah[FI], bh[FJ];
      short8 al[(SPLIT > 0) ? FI : 1], bl[(SPLIT > 0) ? FJ : 1];
#pragma unroll
      for (int i = 0; i < FI; ++i) {
        int r = wm + i * 16 + m16;
        ah[i] = *(const short8*)&AsHi[r * BKT + ks * 32 + kg * 8];
        if (SPLIT > 0 && dos) al[i] = *(const short8*)&AsLo[r * BKT + ks * 32 + kg * 8];
      }
#pragma unroll
      for (int j = 0; j < FJ; ++j) {
        int r = wn + j * 16 + m16;
        bh[j] = *(const short8*)&BsHi[r * BKT + ks * 32 + kg * 8];
        if (SPLIT > 0 && dos) bl[j] = *(const short8*)&BsLo[r * BKT + ks * 32 + kg * 8];
      }
#pragma unroll
      for (int i = 0; i < FI; ++i)
#pragma unroll
        for (int j = 0; j < FJ; ++j) {
          acc[i][j] = __builtin_amdgcn_mfma_f32_16x16x32_bf16(ah[i], bh[j], acc[i][j], 0, 0, 0);
          if (SPLIT > 0) {
            if (dos) {
              acc[i][j] = __builtin_amdgcn_mfma_f32_16x16x32_bf16(al[i], bh[j], acc[i][j], 0, 0, 0);
              acc[i][j] = __builtin_amdgcn_mfma_f32_16x16x32_bf16(ah[i], bl[j], acc[i][j], 0, 0, 0);
            }
          }
        }
    }
    __syncthreads();
  }

  // epilogue: C/D map col=lane&15, row=(lane>>4)*4+reg
#pragma unroll
  for (int i = 0; i < FI; ++i) {
    int gr0 = bm + wm + i * 16 + kg * 4;
#pragma unroll
    for (int j = 0; j < FJ; ++j) {
      int gc = bn + wn + j * 16 + m16;
      float bsv = bias[gc];
#pragma unroll
      for (int r = 0; r < 4; ++r) {
        size_t idx = (size_t)(gr0 + r) * N + gc;
        float v = acc[i][j][r] + bsv;
        if constexpr (EPI == 1) v += res[idx];
        if constexpr (EPI == 2) v = gelu_tanh(v);
        if constexpr (OUTBF16) ((unsigned short*)outp)[idx] = f2bf(v);
        else ((float*)outp)[idx] = v;
      }
    }
  }
}

// ---------------- fused hash+RoPE+expmap0 + windowed Poincare attention ----------------
// block = (b, h, 32-query tile). Stable fp32 score chain via Mobius identities:
//   z^2 = c*||x-y||^2/den,  1-z^2 = (1-c x^2)(1-c y^2)/den,  den = 1-2c<x,y>+c^2 x^2 y^2
//   dist = log((1+z)^2/(1-z^2))/sqrt(c)   [= 2 atanh(z)/sqrt(c)]
// sech^2 terms computed from exp(-2t) (no 1-tanh^2 cancellation).
__global__ __launch_bounds__(256) void attn_fused(const float* __restrict__ qkv,
                                                  const float* __restrict__ fcos,
                                                  const float* __restrict__ fsin,
                                                  const float* __restrict__ cvec,
                                                  const float* __restrict__ geo,
                                                  const float* __restrict__ hash,
                                                  unsigned short* __restrict__ attn_out) {
  __shared__ unsigned short Qhi[32][72], Qlo[32][72];   // pad 72: 144B stride, 2-way only
  __shared__ unsigned short Khi[96][72], Klo[96][72];
  __shared__ unsigned short Vt[64][104];                // V^T [d][key], bf16
  __shared__ unsigned short Pb[32][104];                // softmax weights [query][key]
  __shared__ float Sf[32][97];
  __shared__ float x2s[32], bxs[32], y2s[96], gys[96];

  int tid = threadIdx.x, lane = tid & 63, wv = tid >> 6;
  int bid = blockIdx.x;  // 512 = B*NH*(N/32)
  int nt = bid & 31, h = (bid >> 5) & 7, b = bid >> 8;
  int n0 = nt * 32;
  float c = cvec[b];
  float sqc = sqrtf(c);
  float rsqc = 1.f / sqc;
  float gs = geo[h];
  int dr = lane & 31;
  bool hih = lane >= 32;
  const float LOG9 = 2.1972245773362196f;
  float hofr = hash[h * HDn + dr] * LOG9;
  float hofi = hash[h * HDn + dr + 32] * LOG9;

  // zero P (banded writes later)
  for (int i = tid; i < 32 * 52; i += 256) ((uint32_t*)Pb)[i] = 0u;

  // --- stage Q (8 rows/wave): hash + rope + expmap0, split bf16 + x2/sech2 ---
#pragma unroll
  for (int i = 0; i < 8; ++i) {
    int q = wv * 8 + i;
    int n = n0 + q;
    size_t bas = (size_t)(b * Nn + n) * QKVS + h * HDn;
    float qr = qkv[bas + dr] + hofr;
    float qi = qkv[bas + dr + 32] + hofi;
    float cs = fcos[n * 32 + dr], sn = fsin[n * 32 + dr];
    float qv = hih ? (qr * sn + qi * cs) : (qr * cs - qi * sn);
    float nq = sqrtf(wsum(qv * qv));
    float sq = fmaxf(nq, EPSF);
    float t = sqc * sq;
    float em = expf(-2.f * t);
    float opem = 1.f + em;
    float mag = ((1.f - em) / opem) * rsqc;          // tanh(t)/sqc
    float sech2 = 4.f * em / (opem * opem);          // 1 - c*mag^2, stable
    float oq = (nq < EPSF) ? 0.f : mag * (qv / sq);
    unsigned short hh = f2bf(oq);
    Qhi[q][lane] = hh;
    Qlo[q][lane] = f2bf(oq - bf2f(hh));
    if (lane == 0) {
      x2s[q] = (nq < EPSF) ? 0.f : mag * mag;
      bxs[q] = (nq < EPSF) ? 1.f : sech2;
    }
  }
  // --- stage K (rope + expmap0, split bf16 + y2/sech2) and V^T (bf16), 24 rows/wave ---
#pragma unroll 4
  for (int i = 0; i < 24; ++i) {
    int r = wv * 24 + i;
    int gi = n0 - 64 + r;
    float ok = 0.f, vf = 0.f, y2 = 0.f, gy = 1.f;
    if (gi >= 0) {
      size_t bas = (size_t)(b * Nn + gi) * QKVS + h * HDn;
      float kr = qkv[bas + 512 + dr];
      float ki = qkv[bas + 512 + dr + 32];
      vf = qkv[bas + 1024 + lane];
      float cs = fcos[gi * 32 + dr], sn = fsin[gi * 32 + dr];
      float kv = hih ? (kr * sn + ki * cs) : (kr * cs - ki * sn);
      float nk = sqrtf(wsum(kv * kv));
      float sk = fmaxf(nk, EPSF);
      float t = sqc * sk;
      float em = expf(-2.f * t);
      float opem = 1.f + em;
      float mag = ((1.f - em) / opem) * rsqc;
      float sech2 = 4.f * em / (opem * opem);
      ok = (nk < EPSF) ? 0.f : mag * (kv / sk);
      y2 = (nk < EPSF) ? 0.f : mag * mag;
      gy = (nk < EPSF) ? 1.f : sech2;
    }
    unsigned short hh = f2bf(ok);
    Khi[r][lane] = hh;
    Klo[r][lane] = f2bf(ok - bf2f(hh));
    Vt[lane][r] = f2bf(vf);
    if (lane == 0) { y2s[r] = y2; gys[r] = gy; }
  }
  __syncthreads();

  // --- S = Q K^T via split-bf16 MFMA: M=32 (2 tiles), N=96 (6 tiles), K=64 ---
  int m16 = lane & 15, kg = lane >> 4;
  int mt = wv >> 1;
#pragma unroll
  for (int j = 0; j < 3; ++j) {
    int ntile = (wv & 1) * 3 + j;
    floatx4 acc = {0.f, 0.f, 0.f, 0.f};
#pragma unroll
    for (int ks = 0; ks < 2; ++ks) {
      short8 ah = *(const short8*)&Qhi[mt * 16 + m16][ks * 32 + kg * 8];
      short8 al = *(const short8*)&Qlo[mt * 16 + m16][ks * 32 + kg * 8];
      short8 bh = *(const short8*)&Khi[ntile * 16 + m16][ks * 32 + kg * 8];
      short8 bl = *(const short8*)&Klo[ntile * 16 + m16][ks * 32 + kg * 8];
      acc = __builtin_amdgcn_mfma_f32_16x16x32_bf16(ah, bh, acc, 0, 0, 0);
      acc = __builtin_amdgcn_mfma_f32_16x16x32_bf16(al, bh, acc, 0, 0, 0);
      acc = __builtin_amdgcn_mfma_f32_16x16x32_bf16(ah, bl, acc, 0, 0, 0);
    }
#pragma unroll
    for (int r = 0; r < 4; ++r) Sf[mt * 16 + kg * 4 + r][ntile * 16 + m16] = acc[r];
  }
  __syncthreads();

  // --- stable fp32 scores + softmax -> Pb bf16 (own rows only) ---
  for (int i = 0; i < 8; ++i) {
    int nl = wv * 8 + i;
    int r = nl + 1 + lane;  // key row in [1,95]
    float xy = Sf[nl][r];
    float x2 = x2s[nl], y2 = y2s[r];
    float bx = bxs[nl], gy = gys[r];

    float den = fmaf(c * c * x2, y2, fmaf(-2.f * c, xy, 1.f));
    den = fmaxf(den, EPSF);
    float rden = 1.f / den;
    float s2 = fmaxf(x2 - 2.f * xy + y2, 0.f);       // ||x-y||^2
    float z = sqrtf(c * s2 * rden);
    float omz2 = bx * gy * rden;                     // 1 - z^2 (positive, stable)
    float opz = 1.f + fminf(z, 1.f);
    float ratio = fminf(opz * opz / omz2, 1.9999999e7f);  // (1+z)/(1-z), clamp at arg=1-1e-7
    float sc = -gs * logf(ratio) * rsqc;

    float mx = wmax(sc);
    float e = expf(sc - mx);
    float se = wsum(e);
    Pb[nl][r] = f2bf(e / se);
  }
  __syncthreads();

  // --- PV via MFMA: P[32x96] x Vt -> O[32x64]; 2 n-tiles per wave ---
#pragma unroll
  for (int nt2 = 0; nt2 < 2; ++nt2) {
    int ntile = (wv & 1) * 2 + nt2;
    floatx4 acc = {0.f, 0.f, 0.f, 0.f};
#pragma unroll
    for (int ks = 0; ks < 3; ++ks) {
      short8 a = *(const short8*)&Pb[mt * 16 + m16][ks * 32 + kg * 8];
      short8 bb = *(const short8*)&Vt[ntile * 16 + m16][ks * 32 + kg * 8];
      acc = __builtin_amdgcn_mfma_f32_16x16x32_bf16(a, bb, acc, 0, 0, 0);
    }
#pragma unroll
    for (int r = 0; r < 4; ++r) {
      int qrow = mt * 16 + kg * 4 + r;
      int d = ntile * 16 + m16;
      attn_out[(size_t)(b * Nn + n0 + qrow) * DIMn + h * HDn + d] = f2bf(acc[r]);
    }
  }
}

// ---------------- launcher ----------------
extern "C" void kernel_launch(void* const* d_in, const int* in_sizes, int n_in,
                              void* d_out, int out_size, void* d_ws, size_t ws_size,
                              hipStream_t stream) {
  const float* x    = (const float*)d_in[0];
  const float* fcos = (const float*)d_in[1];
  const float* fsin = (const float*)d_in[2];
  const float* cvec = (const float*)d_in[3];
  const float* Wq = (const float*)d_in[4];  const float* bq = (const float*)d_in[5];
  const float* Wk = (const float*)d_in[6];  const float* bk = (const float*)d_in[7];
  const float* Wv = (const float*)d_in[8];  const float* bv = (const float*)d_in[9];
  const float* Wo = (const float*)d_in[10]; const float* bo = (const float*)d_in[11];
  const float* W1 = (const float*)d_in[12]; const float* b1 = (const float*)d_in[13];
  const float* W2 = (const float*)d_in[14]; const float* b2 = (const float*)d_in[15];
  const float* ln1s = (const float*)d_in[16]; const float* ln1b = (const float*)d_in[17];
  const float* ln2s = (const float*)d_in[18]; const float* ln2b = (const float*)d_in[19];
  const float* geo  = (const float*)d_in[20]; const float* hash = (const float*)d_in[21];
  float* out = (float*)d_out;
  char* base = (char*)d_ws;

  unsigned short* Wcat_hi = (unsigned short*)(base + 0);         // 1536x512 bf16
  unsigned short* Wcat_lo = (unsigned short*)(base + 1572864);
  unsigned short* Wo_t    = (unsigned short*)(base + 3145728);   // 512x512
  unsigned short* W1_t    = (unsigned short*)(base + 3670016);   // 2048x512
  unsigned short* W2_t    = (unsigned short*)(base + 5767168);   // 512x2048
  unsigned short* xn_hi   = (unsigned short*)(base + 7864320);   // 2048x512
  unsigned short* xn_lo   = (unsigned short*)(base + 9961472);
  float*          qkv     = (float*)(base + 12058624);           // 2048x1536 f32
  unsigned short* attnb   = (unsigned short*)(base + 7864320);   // reuse xn_hi
  float*          xout    = (float*)(base + 9961472);            // 2048x512 f32 (reuse)
  unsigned short* hbuf    = (unsigned short*)(base + 14155776);  // 2048x512
  unsigned short* mid     = (unsigned short*)(base + 16252928);  // 2048x2048
  float*          bias_cat= (float*)(base + 24641536);           // 1536 f32

  const int M = Bn * Nn;  // 2048

  convT_all<<<3073, 256, 0, stream>>>(Wq, Wk, Wv, Wo, W1, W2, Wcat_hi, Wcat_lo,
                                      Wo_t, W1_t, W2_t, bq, bk, bv, bias_cat);
  ln_kernel<1><<<M, 256, 0, stream>>>(x, ln1s, ln1b, xn_hi, xn_lo);
  // QKV GEMM, hybrid split (q,k split / v plain), 64x64 tile -> grid 24x32 = 768
  gemm_mfma<64, 64, 32, 2, 0, 0><<<dim3(QKVS / 64, M / 64), 256, 0, stream>>>(
      xn_hi, xn_lo, Wcat_hi, Wcat_lo, bias_cat, nullptr, qkv, M, QKVS, 512);
  // fused rope + windowed Poincare attention -> attnb bf16 [M][512]
  attn_fused<<<Bn * NHn * (Nn / 32), 256, 0, stream>>>(qkv, fcos, fsin, cvec, geo, hash, attnb);
  // Wo + residual(x) -> xout f32; 32x64 tile, BK=64 -> grid 8x64 = 512
  gemm_mfma<32, 64, 64, 0, 1, 0><<<dim3(DIMn / 64, M / 32), 256, 0, stream>>>(
      attnb, nullptr, Wo_t, nullptr, bo, x, xout, M, DIMn, 512);
  ln_kernel<0><<<M, 256, 0, stream>>>(xout, ln2s, ln2b, hbuf, nullptr);
  // FFN1 + gelu -> mid bf16; 64x128 tile, BK=64 -> grid 16x32 = 512
  gemm_mfma<64, 128, 64, 0, 2, 1><<<dim3(2048 / 128, M / 64), 256, 0, stream>>>(
      hbuf, nullptr, W1_t, nullptr, b1, nullptr, mid, M, 2048, 512);
  // FFN2 + residual(xout) -> out f32; 32x64 tile, BK=64 -> grid 8x64 = 512
  gemm_mfma<32, 64, 64, 0, 1, 0><<<dim3(DIMn / 64, M / 32), 256, 0, stream>>>(
      mid, nullptr, W2_t, nullptr, b2, xout, out, M, DIMn, 2048);
}